// Round 18
// baseline (265.434 us; speedup 1.0000x reference)
//
#include <hip/hip_runtime.h>
#include <math.h>

constexpr int B = 32, N = 1024, ND = 8, FEAT = 2048, WVD = 300;
constexpr int E = 20000, T = 2, STEPS = 5;
constexpr int NDIM = N * ND;            // 8192
constexpr int H1 = 512;
constexpr int W1C = FEAT + WVD;         // 2348
constexpr int EMB = 50;
constexpr int RC = EMB * ND * ND;       // 3200
constexpr int KH = 150;                 // Wv k-split half
constexpr int CAP = 64;                 // fixed row capacity (P(row>64)~1e-20)
constexpr int SEG = 50;                 // fine segments for skip-scan
constexpr int SEGLEN = E / SEG;         // 400 (not mult of 64 — guard)

// k_f1 sections
constexpr int G_KA   = 512;
constexpr int G_W1T  = 16 * 10;
constexpr int G_EMB  = N * 25 / 4;         // 6400
constexpr int G_SEGH = T * N * SEG / 4;    // 25600
constexpr int F1_TOT = G_KA + G_W1T + G_EMB + G_SEGH;

// k_f2 sections
constexpr int G_ARED = 8;
constexpr int G_WV   = 512;
constexpr int G_AHAT = 13 * 32 * T;        // 832
constexpr int F2_TOT = G_ARED + G_WV + G_AHAT;

// k_f3 sections: 2048 row blocks (one per (t,u)) + 256 inputnet blocks
constexpr int G_ROW  = T * N;
constexpr int G_INP  = N / 4;
constexpr int F3_TOT = G_ROW + G_INP;

// ============ F1: k_A GEMM | W1-transpose | embs(+embsT) | seghist(50) ============
__global__ __launch_bounds__(256) void k_f1(
        const int* eu, int* segcnt,
        const float* inp, const float* W1, float* partA, float* W1T,
        const float* wv, const float* We, const float* be,
        float* embs, float* embsT) {
    __shared__ float smem[8 * 260];
    int tid = threadIdx.x;
    int blk = blockIdx.x;
    if (blk < G_KA) {
        int c = tid & 7, b = tid >> 3;
        int c0 = (blk & 63) * 8;
        int ks = blk >> 6;
        int kt = ks * 256;
        {
            int r = tid >> 5, cb = (tid & 31) * 8;
            const float* src = W1 + (size_t)(c0 + r) * W1C + kt + cb;
            float4 a0 = *(const float4*)src;
            float4 a1 = *(const float4*)(src + 4);
            *(float4*)&smem[r * 260 + cb] = a0;
            *(float4*)&smem[r * 260 + cb + 4] = a1;
        }
        __syncthreads();
        const float* xr = inp + (size_t)b * FEAT + kt;
        float acc = 0.f;
#pragma unroll 8
        for (int k4 = 0; k4 < 64; k4++) {
            float4 x = *(const float4*)(xr + k4 * 4);
            float4 w = *(const float4*)&smem[c * 260 + k4 * 4];
            acc += x.x * w.x + x.y * w.y + x.z * w.z + x.w * w.w;
        }
        partA[(size_t)ks * (H1 * B) + (c0 + c) * B + b] = acc;
    } else if (blk < G_KA + G_W1T) {
        int lb = blk - G_KA;
        int c0 = (lb % 16) * 32, k0 = (lb / 16) * 32;
        float (*tile)[33] = (float(*)[33])smem;
        int kl = tid & 31, cl4 = tid >> 5;
#pragma unroll
        for (int p = 0; p < 4; p++) {
            int c = cl4 + p * 8;
            int k = k0 + kl;
            if (k < WVD) tile[c][kl] = W1[(size_t)(c0 + c) * W1C + FEAT + k];
        }
        __syncthreads();
        int cl = tid & 31, kl4 = tid >> 5;
#pragma unroll
        for (int p = 0; p < 4; p++) {
            int kk = kl4 + p * 8;
            int k = k0 + kk;
            if (k < WVD) W1T[(size_t)k * H1 + c0 + cl] = tile[cl][kk];
        }
    } else if (blk < G_KA + G_W1T + G_EMB) {
        int lb = blk - G_KA - G_W1T;
        int wid = lb * 4 + (tid >> 6);
        int lane = tid & 63;
        int n = wid / 25, cp = wid - n * 25;
        int c0 = cp * 2;
        const float* xr = wv + (size_t)n * WVD;
        const float* wr0 = We + (size_t)c0 * WVD;
        const float* wr1 = wr0 + WVD;
        float a0 = 0.f, a1 = 0.f;
#pragma unroll
        for (int i = 0; i < 5; i++) {
            int k = i * 64 + lane;
            if (k < WVD) {
                float x = xr[k];
                a0 += x * wr0[k];
                a1 += x * wr1[k];
            }
        }
        for (int m = 32; m; m >>= 1) {
            a0 += __shfl_xor(a0, m, 64);
            a1 += __shfl_xor(a1, m, 64);
        }
        if (lane == 0) {
            float v0 = a0 + be[c0], v1 = a1 + be[c0 + 1];
            embs[n * EMB + c0] = v0;
            embs[n * EMB + c0 + 1] = v1;
            embsT[c0 * N + n] = v0;
            embsT[(c0 + 1) * N + n] = v1;
        }
    } else {
        int lb = blk - G_KA - G_W1T - G_EMB;
        int wid = lb * 4 + (tid >> 6);
        int lane = tid & 63;
        int t = wid / (N * SEG);
        int rem = wid - t * (N * SEG);
        int u = rem / SEG, seg = rem - u * SEG;
        const int* eut = eu + t * E;
        int e0 = seg * SEGLEN, e1 = e0 + SEGLEN, cnt = 0;
        for (int c = e0; c < e1; c += 64) {
            int e = c + lane;
            bool ok = (e < e1) && (eut[e] == u);
            cnt += __popcll(__ballot(ok));
        }
        if (lane == 0) segcnt[(t * N + u) * SEG + seg] = cnt;
    }
}

// ============ F2: partA-reduce | Wv GEMM | Ahat GEMM ============
__global__ __launch_bounds__(256) void k_f2(
        const float* partA, float* AbT,
        const float* wv, const float* W1T, float* Wp,
        const float* embsT, const float* RMbase, float* Ahat) {
    __shared__ float smemf[1800];
    int tid = threadIdx.x, blk = blockIdx.x;
    if (blk < G_ARED) {
        int cb = blk * 2048 + tid * 8;
        float4 s0 = {0, 0, 0, 0}, s1 = {0, 0, 0, 0};
#pragma unroll
        for (int ks = 0; ks < 8; ks++) {
            const float* p = partA + (size_t)ks * (H1 * B) + cb;
            float4 a = *(const float4*)p;
            float4 b4 = *(const float4*)(p + 4);
            s0.x += a.x; s0.y += a.y; s0.z += a.z; s0.w += a.w;
            s1.x += b4.x; s1.y += b4.y; s1.z += b4.z; s1.w += b4.w;
        }
        *(float4*)(AbT + cb) = s0;
        *(float4*)(AbT + cb + 4) = s1;
    } else if (blk < G_ARED + G_WV) {
        int lb = blk - G_ARED;
        int kh = lb >> 8;
        int rem = lb & 255;
        int c = (rem & 1) * 256 + tid;
        int n0 = (rem >> 1) * 8;
        int kb = kh * KH;
        float (*el)[8] = (float(*)[8])smemf;
        for (int idx = tid; idx < 8 * KH; idx += 256) {
            int j = idx / KH, k = idx - j * KH;
            el[k][j] = wv[(size_t)(n0 + j) * WVD + kb + k];
        }
        __syncthreads();
        float acc[8] = {};
#pragma unroll 5
        for (int k = 0; k < KH; k++) {
            float r = W1T[(size_t)(kb + k) * H1 + c];
            float4 e0 = *(const float4*)&el[k][0];
            float4 e1 = *(const float4*)&el[k][4];
            acc[0] += e0.x * r; acc[1] += e0.y * r;
            acc[2] += e0.z * r; acc[3] += e0.w * r;
            acc[4] += e1.x * r; acc[5] += e1.y * r;
            acc[6] += e1.z * r; acc[7] += e1.w * r;
        }
        float* wout = Wp + (size_t)kh * N * H1;
#pragma unroll
        for (int j = 0; j < 8; j++) wout[(size_t)(n0 + j) * H1 + c] = acc[j];
    } else {
        int lb = blk - G_ARED - G_WV;
        int t = lb / 416, r = lb % 416;
        int bx = r % 13, by = r / 13;
        const float* RM = RMbase + (size_t)t * EMB * RC;
        float* Ah = Ahat + (size_t)t * N * RC;
        int n0 = by * 32;
        float (*el)[36] = (float(*)[36])smemf;
        for (int idx = tid; idx < EMB * 32; idx += 256)
            el[idx >> 5][idx & 31] = embsT[(idx >> 5) * N + n0 + (idx & 31)];
        __syncthreads();
        int mi = bx * 256 + (tid & 63) * 4;
        int ni = (tid >> 6) * 8;
        if (mi < RC) {
            float acc[8][4] = {};
#pragma unroll 2
            for (int c = 0; c < EMB; c++) {
                float4 rm = *(const float4*)(RM + (size_t)c * RC + mi);
                float4 e0 = *(const float4*)&el[c][ni];
                float4 e1 = *(const float4*)&el[c][ni + 4];
                float ev[8] = {e0.x, e0.y, e0.z, e0.w, e1.x, e1.y, e1.z, e1.w};
#pragma unroll
                for (int j = 0; j < 8; j++) {
                    acc[j][0] += ev[j] * rm.x;
                    acc[j][1] += ev[j] * rm.y;
                    acc[j][2] += ev[j] * rm.z;
                    acc[j][3] += ev[j] * rm.w;
                }
            }
#pragma unroll
            for (int j = 0; j < 8; j++) {
                float4 o = {acc[j][0], acc[j][1], acc[j][2], acc[j][3]};
                *(float4*)(Ah + (size_t)(n0 + ni + j) * RC + mi) = o;
            }
        }
    }
}

// ============ F3: [blk<2N] per-(t,u) build + weights + pssq
//              [blk>=2N] inputnet (4 n per block) ============
__global__ __launch_bounds__(256) void k_f3(
        const int* eu, const int* ev, const int* segcnt,
        const float* embs, const float* Ahat, float* wbuf, float* pssq,
        int* counts, int* sv,
        const float* AbT, const float* Wp, const float* b1,
        const float* W2, const float* b2, float* sT0) {
    __shared__ float smem[6656];   // carved per branch
    int tid = threadIdx.x;
    int blk = blockIdx.x;
    if (blk < G_ROW) {
        int t = blk >> 10, u = blk & (N - 1);
        int row = t * N + u;
        float* AL  = smem;                      // 3200 floats
        int* vl    = (int*)(smem + 3200);       // 64
        int* scnt  = vl + CAP;                  // 50
        int* soff  = scnt + SEG;                // 50
        int* slist = soff + SEG;                // 50
        int* meta  = slist + SEG;               // [0]=nnz [1]=cnt
        int w = tid >> 6, lane = tid & 63;
        if (tid < SEG) scnt[tid] = segcnt[(size_t)row * SEG + tid];
        __syncthreads();
        if (tid == 0) {
            int off = 0, nn = 0;
            for (int j = 0; j < SEG; j++) {
                int c = scnt[j];
                soff[j] = off;
                off += c;
                if (c > 0) slist[nn++] = j;
            }
            meta[0] = nn;
            meta[1] = off;
            counts[row] = off;
        }
        __syncthreads();
        int nnz = meta[0], cnt = meta[1];
        const int* eut = eu + t * E;
        const int* evt = ev + t * E;
        for (int idx = w; idx < nnz; idx += 4) {
            int seg = slist[idx];
            int sbase = soff[seg];
            int e0 = seg * SEGLEN, e1 = e0 + SEGLEN, c2 = 0;
            for (int c = e0; c < e1; c += 64) {
                int e = c + lane;
                bool ok = (e < e1) && (eut[e] == u);
                unsigned long long m = __ballot(ok);
                if (ok) {
                    int rank = __popcll(m & ((1ull << lane) - 1));
                    int pos = sbase + c2 + rank;
                    vl[pos] = evt[e];
                    sv[(size_t)row * CAP + pos] = evt[e];
                }
                c2 += __popcll(m);
            }
        }
        __syncthreads();
        // stage Ahat panel with float4
        {
            const float4* asrc = (const float4*)(Ahat + (size_t)row * RC);
            float4* adst = (float4*)AL;
            for (int idx = tid; idx < RC / 4; idx += 256)
                adst[idx] = asrc[idx];
        }
        __syncthreads();
        int k = lane;
        float ssq = 0.f;
        size_t wbase = (size_t)row * CAP;
        for (int i = w; i < cnt; i += 8) {
            int i2 = i + 4;
            bool h2 = i2 < cnt;
            int v0 = vl[i];
            int v1 = h2 ? vl[i2] : v0;
            const float* vr0 = embs + v0 * EMB;
            const float* vr1 = embs + v1 * EMB;
            float a0 = 0.f, a1 = 0.f;
#pragma unroll 10
            for (int d = 0; d < EMB; d++) {
                float al = AL[d * 64 + k];
                a0 += vr0[d] * al;
                a1 += vr1[d] * al;
            }
            wbuf[(wbase + i) * 64 + k] = a0;
            ssq += a0 * a0;
            if (h2) {
                wbuf[(wbase + i2) * 64 + k] = a1;
                ssq += a1 * a1;
            }
        }
        __syncthreads();
        AL[w * 64 + k] = ssq;
        __syncthreads();
        if (tid < 64) {
            float tot = AL[tid] + AL[64 + tid] + AL[128 + tid] + AL[192 + tid];
            tot += __shfl_xor(tot, 1, 64);
            tot += __shfl_xor(tot, 2, 64);
            tot += __shfl_xor(tot, 4, 64);
            int ki = tid >> 3, kj = tid & 7;
            if (kj == 0)
                pssq[(size_t)t * NDIM + u * ND + ki] = tot;
        }
    } else {
        int n0 = (blk - G_ROW) * 4;
        float* w2s  = smem;            // 4096
        float* wvs  = smem + 4096;     // 512
        float* part = smem + 4608;     // 2048
        for (int idx = tid; idx < 8 * H1; idx += 256) w2s[idx] = W2[idx];
        int b = tid & 31, s = tid >> 5;
        int ki2 = tid >> 5, b2i = tid & 31;
        for (int nn = 0; nn < 4; nn++) {
            int n = n0 + nn;
            __syncthreads();
            for (int idx = tid; idx < H1; idx += 256)
                wvs[idx] = Wp[(size_t)n * H1 + idx]
                         + Wp[(size_t)N * H1 + (size_t)n * H1 + idx] + b1[idx];
            __syncthreads();
            float acc[8] = {};
            for (int i = 0; i < 64; i++) {
                int c = s * 64 + i;
                float tv = fmaxf(AbT[c * 32 + b] + wvs[c], 0.f);
#pragma unroll
                for (int ki = 0; ki < 8; ki++) acc[ki] += tv * w2s[ki * H1 + c];
            }
#pragma unroll
            for (int ki = 0; ki < 8; ki++) part[s * 256 + ki * 32 + b] = acc[ki];
            __syncthreads();
            float tot = b2[ki2];
#pragma unroll
            for (int s2 = 0; s2 < 8; s2++) tot += part[s2 * 256 + ki2 * 32 + b2i];
            sT0[(size_t)n * 256 + tid] = tot;
        }
    }
}

// per-node inverse-norm from partial ssq
__device__ __forceinline__ void getinv(const float* pssq, int v, float* iv) {
    const float* qa = pssq + (size_t)v * ND;
    const float* qb = pssq + (size_t)NDIM + (size_t)v * ND;
#pragma unroll
    for (int j = 0; j < 8; j++) {
        float ns = qa[j] + qb[j];
        iv[j] = (ns == 0.f) ? 1.f : rsqrtf(ns);
    }
}

// ============ propagation step ============
// s==0 launch: grid N+8; blocks N..N+7 write inorm (for steps 1..4); row blocks
// use pssq directly. s>0: grid N, row blocks use precomputed inorm.
__global__ __launch_bounds__(256) void k_step(
        const int* counts, const int* sv,
        const float* wbuf, const float* pssq, float* inorm, const float* sT, int s,
        const float* W_ih, const float* W_hh, const float* b_ih, const float* b_hh,
        const float* Wo1, const float* bo1, const float* Wo2, const float* bo2,
        float* sOut, float* out, int last) {
    int tid = threadIdx.x;
    if (blockIdx.x >= N) {               // inorm writers (s==0 launch only)
        int i4 = ((blockIdx.x - N) * 256 + tid) * 4;
        float4 qa = *(const float4*)(pssq + i4);
        float4 qb = *(const float4*)(pssq + NDIM + i4);
        float4 o;
        float n0 = qa.x + qb.x, n1 = qa.y + qb.y, n2 = qa.z + qb.z, n3 = qa.w + qb.w;
        o.x = (n0 == 0.f) ? 1.f : rsqrtf(n0);
        o.y = (n1 == 0.f) ? 1.f : rsqrtf(n1);
        o.z = (n2 == 0.f) ? 1.f : rsqrtf(n2);
        o.w = (n3 == 0.f) ? 1.f : rsqrtf(n3);
        *(float4*)(inorm + i4) = o;
        return;
    }
    __shared__ float xs[256], hs[256], hfin[256];
    __shared__ float wih[192], whh[192];
    __shared__ float w1s[160], b1s[20], w2s[20];
    __shared__ float res[8][33];
    int u = blockIdx.x;
    int ki = tid >> 5, b = tid & 31;
    int first = (s == 0);
    if (tid < 192) { wih[tid] = W_ih[tid]; whh[tid] = W_hh[tid]; }
    if (last) {
        if (tid < 160) w1s[tid] = Wo1[tid];
        if (tid < 20) { b1s[tid] = bo1[tid]; w2s[tid] = Wo2[tid]; }
    }
    const float* sIn = sT + (size_t)s * NDIM * B;
    float hown = sIn[((size_t)u * 8 + ki) * B + b];
    float acc = 0.f;
    for (int t = 0; t < T; t++) {
        int row = t * N + u;
        int cnt = counts[row];
        size_t base = (size_t)row * CAP;
        int i = 0;
        for (; i + 1 < cnt; i += 2) {
            size_t s0 = base + i, s1 = base + i + 1;
            int v0 = sv[s0], v1 = sv[s1];
            const float* wp0 = wbuf + s0 * 64 + ki * 8;
            const float* wp1 = wbuf + s1 * 64 + ki * 8;
            float4 wa0 = *(const float4*)wp0;
            float4 wb0 = *(const float4*)(wp0 + 4);
            float4 wa1 = *(const float4*)wp1;
            float4 wb1 = *(const float4*)(wp1 + 4);
            float iv0[8], iv1[8];
            if (first) {
                getinv(pssq, v0, iv0);
                getinv(pssq, v1, iv1);
            } else {
                const float* p0 = inorm + v0 * ND;
                const float* p1 = inorm + v1 * ND;
#pragma unroll
                for (int j = 0; j < 8; j++) { iv0[j] = p0[j]; iv1[j] = p1[j]; }
            }
            const float* hp0 = sIn + (size_t)v0 * 256 + b;
            const float* hp1 = sIn + (size_t)v1 * 256 + b;
            acc += (wa0.x * iv0[0]) * hp0[0]   + (wa0.y * iv0[1]) * hp0[32]
                 + (wa0.z * iv0[2]) * hp0[64]  + (wa0.w * iv0[3]) * hp0[96]
                 + (wb0.x * iv0[4]) * hp0[128] + (wb0.y * iv0[5]) * hp0[160]
                 + (wb0.z * iv0[6]) * hp0[192] + (wb0.w * iv0[7]) * hp0[224];
            acc += (wa1.x * iv1[0]) * hp1[0]   + (wa1.y * iv1[1]) * hp1[32]
                 + (wa1.z * iv1[2]) * hp1[64]  + (wa1.w * iv1[3]) * hp1[96]
                 + (wb1.x * iv1[4]) * hp1[128] + (wb1.y * iv1[5]) * hp1[160]
                 + (wb1.z * iv1[6]) * hp1[192] + (wb1.w * iv1[7]) * hp1[224];
        }
        if (i < cnt) {
            size_t s0 = base + i;
            int v0 = sv[s0];
            const float* wp0 = wbuf + s0 * 64 + ki * 8;
            float4 wa0 = *(const float4*)wp0;
            float4 wb0 = *(const float4*)(wp0 + 4);
            float iv0[8];
            if (first) {
                getinv(pssq, v0, iv0);
            } else {
                const float* p0 = inorm + v0 * ND;
#pragma unroll
                for (int j = 0; j < 8; j++) iv0[j] = p0[j];
            }
            const float* hp0 = sIn + (size_t)v0 * 256 + b;
            acc += (wa0.x * iv0[0]) * hp0[0]   + (wa0.y * iv0[1]) * hp0[32]
                 + (wa0.z * iv0[2]) * hp0[64]  + (wa0.w * iv0[3]) * hp0[96]
                 + (wb0.x * iv0[4]) * hp0[128] + (wb0.y * iv0[5]) * hp0[160]
                 + (wb0.z * iv0[6]) * hp0[192] + (wb0.w * iv0[7]) * hp0[224];
        }
    }
    float xv = tanhf(acc);
    xs[ki * 32 + b] = xv;
    hs[ki * 32 + b] = hown;
    __syncthreads();
    float gr = b_ih[ki], gz = b_ih[8 + ki], gn = b_ih[16 + ki];
    float hr = b_hh[ki], hz = b_hh[8 + ki], hn = b_hh[16 + ki];
#pragma unroll
    for (int j = 0; j < 8; j++) {
        float xj = xs[j * 32 + b], hj = hs[j * 32 + b];
        gr += wih[ki * 8 + j] * xj;
        gz += wih[(8 + ki) * 8 + j] * xj;
        gn += wih[(16 + ki) * 8 + j] * xj;
        hr += whh[ki * 8 + j] * hj;
        hz += whh[(8 + ki) * 8 + j] * hj;
        hn += whh[(16 + ki) * 8 + j] * hj;
    }
    float r = 1.f / (1.f + expf(-(gr + hr)));
    float z = 1.f / (1.f + expf(-(gz + hz)));
    float nn = tanhf(gn + r * hn);
    float hnew = (1.f - z) * nn + z * hown;
    if (!last) {
        sOut[((size_t)u * 8 + ki) * B + b] = hnew;
        return;
    }
    hfin[ki * 32 + b] = hnew;
    __syncthreads();
    int s6 = tid >> 5, bb = tid & 31;
    if (s6 < 6) {
        float x[8];
#pragma unroll
        for (int kk = 0; kk < 8; kk++)
            x[kk] = (s6 < STEPS)
                ? sT[((size_t)s6 * NDIM + u * 8 + kk) * B + bb]
                : hfin[kk * 32 + bb];
        float accv = bo2[0];
#pragma unroll
        for (int j = 0; j < 20; j++) {
            float h = b1s[j];
#pragma unroll
            for (int kk = 0; kk < 8; kk++) h += w1s[j * 8 + kk] * x[kk];
            h = fmaxf(h, 0.f);
            accv += w2s[j] * h;
        }
        res[s6][bb] = accv;
    }
    __syncthreads();
    if (tid < 192) {
        int b_w = tid / 6, s_w = tid - b_w * 6;
        out[(size_t)b_w * ((STEPS + 1) * N) + u * (STEPS + 1) + s_w] = res[s_w][b_w];
    }
}

extern "C" void kernel_launch(void* const* d_in, const int* in_sizes, int n_in,
                              void* d_out, int out_size, void* d_ws, size_t ws_size,
                              hipStream_t stream) {
    const float* inputs   = (const float*)d_in[0];
    const float* wordvecs = (const float*)d_in[1];
    const int*   edge_u   = (const int*)d_in[2];
    const int*   edge_v   = (const int*)d_in[3];
    const float* W_in1 = (const float*)d_in[6];
    const float* b_in1 = (const float*)d_in[7];
    const float* W_in2 = (const float*)d_in[8];
    const float* b_in2 = (const float*)d_in[9];
    const float* W_emb = (const float*)d_in[10];
    const float* b_emb = (const float*)d_in[11];
    const float* rel_mats = (const float*)d_in[12];
    const float* W_ih = (const float*)d_in[13];
    const float* W_hh = (const float*)d_in[14];
    const float* b_ih = (const float*)d_in[15];
    const float* b_hh = (const float*)d_in[16];
    const float* W_o1 = (const float*)d_in[17];
    const float* b_o1 = (const float*)d_in[18];
    const float* W_o2 = (const float*)d_in[19];
    const float* b_o2 = (const float*)d_in[20];
    float* out = (float*)d_out;

    char* ws = (char*)d_ws;
    size_t off = 0;
    auto alloc = [&](size_t bytes) -> void* {
        void* p = ws + off;
        off = (off + bytes + 255) & ~(size_t)255;
        return p;
    };
    int* segcnt    = (int*)alloc((size_t)T * N * SEG * 4);
    int* counts    = (int*)alloc(2048 * 4);
    int* sv        = (int*)alloc((size_t)T * N * CAP * 4);
    float* pssq    = (float*)alloc((size_t)T * NDIM * 4);
    float* inorm   = (float*)alloc((size_t)NDIM * 4);
    float* partA   = (float*)alloc((size_t)8 * H1 * B * 4);
    float* AbT     = (float*)alloc((size_t)H1 * B * 4);
    float* W1T     = (float*)alloc((size_t)WVD * H1 * 4);
    float* Wp      = (float*)alloc((size_t)2 * N * H1 * 4);
    float* embs    = (float*)alloc((size_t)N * EMB * 4);
    float* embsT   = (float*)alloc((size_t)EMB * N * 4);
    float* Ahat    = (float*)alloc((size_t)T * N * RC * 4);
    float* wbuf    = (float*)alloc((size_t)T * N * CAP * 64 * 4);
    float* sT      = (float*)alloc((size_t)(STEPS + 1) * NDIM * B * 4);

    k_f1<<<F1_TOT, 256, 0, stream>>>(edge_u, segcnt, inputs, W_in1, partA, W1T,
                                     wordvecs, W_emb, b_emb, embs, embsT);
    k_f2<<<F2_TOT, 256, 0, stream>>>(partA, AbT, wordvecs, W1T, Wp,
                                     embsT, rel_mats, Ahat);
    k_f3<<<F3_TOT, 256, 0, stream>>>(edge_u, edge_v, segcnt,
                                     embs, Ahat, wbuf, pssq, counts, sv,
                                     AbT, Wp, b_in1, W_in2, b_in2, sT);

    for (int s = 0; s < STEPS; s++) {
        int last = (s == STEPS - 1) ? 1 : 0;
        int grid = (s == 0) ? (N + 8) : N;
        k_step<<<grid, 256, 0, stream>>>(counts, sv, wbuf, pssq, inorm, sT, s,
                                         W_ih, W_hh, b_ih, b_hh,
                                         W_o1, b_o1, W_o2, b_o2,
                                         sT + (size_t)(s + 1) * NDIM * B, out, last);
    }
}

// Round 19
// 262.716 us; speedup vs baseline: 1.0103x; 1.0103x over previous
//
#include <hip/hip_runtime.h>
#include <math.h>

constexpr int B = 32, N = 1024, ND = 8, FEAT = 2048, WVD = 300;
constexpr int E = 20000, T = 2, STEPS = 5;
constexpr int NDIM = N * ND;            // 8192
constexpr int H1 = 512;
constexpr int W1C = FEAT + WVD;         // 2348
constexpr int EMB = 50;
constexpr int RC = EMB * ND * ND;       // 3200
constexpr int KH = 150;                 // Wv k-split half
constexpr int CAP = 64;                 // fixed row capacity (P(row>64)~1e-20)
constexpr int SEG = 50;                 // fine segments for skip-scan
constexpr int SEGLEN = E / SEG;         // 400 (not mult of 64 — guard)

// k_f1 sections
constexpr int G_KA   = 512;
constexpr int G_W1T  = 16 * 10;
constexpr int G_EMB  = N * 25 / 4;         // 6400
constexpr int G_SEGH = T * N * SEG / 4;    // 25600
constexpr int F1_TOT = G_KA + G_W1T + G_EMB + G_SEGH;

// k_f2 sections
constexpr int G_ARED = 8;
constexpr int G_WV   = 512;
constexpr int G_AHAT = 13 * 32 * T;        // 832
constexpr int F2_TOT = G_ARED + G_WV + G_AHAT;

// k_f3 sections: N row blocks (both types per u) + 256 inputnet blocks
constexpr int G_INP  = N / 4;
constexpr int F3_TOT = N + G_INP;

// ============ F1: k_A GEMM | W1-transpose | embs(+embsT) | seghist(50) ============
__global__ __launch_bounds__(256) void k_f1(
        const int* eu, int* segcnt,
        const float* inp, const float* W1, float* partA, float* W1T,
        const float* wv, const float* We, const float* be,
        float* embs, float* embsT) {
    __shared__ float smem[8 * 260];
    int tid = threadIdx.x;
    int blk = blockIdx.x;
    if (blk < G_KA) {
        int c = tid & 7, b = tid >> 3;
        int c0 = (blk & 63) * 8;
        int ks = blk >> 6;
        int kt = ks * 256;
        {
            int r = tid >> 5, cb = (tid & 31) * 8;
            const float* src = W1 + (size_t)(c0 + r) * W1C + kt + cb;
            float4 a0 = *(const float4*)src;
            float4 a1 = *(const float4*)(src + 4);
            *(float4*)&smem[r * 260 + cb] = a0;
            *(float4*)&smem[r * 260 + cb + 4] = a1;
        }
        __syncthreads();
        const float* xr = inp + (size_t)b * FEAT + kt;
        float acc = 0.f;
#pragma unroll 8
        for (int k4 = 0; k4 < 64; k4++) {
            float4 x = *(const float4*)(xr + k4 * 4);
            float4 w = *(const float4*)&smem[c * 260 + k4 * 4];
            acc += x.x * w.x + x.y * w.y + x.z * w.z + x.w * w.w;
        }
        partA[(size_t)ks * (H1 * B) + (c0 + c) * B + b] = acc;
    } else if (blk < G_KA + G_W1T) {
        int lb = blk - G_KA;
        int c0 = (lb % 16) * 32, k0 = (lb / 16) * 32;
        float (*tile)[33] = (float(*)[33])smem;
        int kl = tid & 31, cl4 = tid >> 5;
#pragma unroll
        for (int p = 0; p < 4; p++) {
            int c = cl4 + p * 8;
            int k = k0 + kl;
            if (k < WVD) tile[c][kl] = W1[(size_t)(c0 + c) * W1C + FEAT + k];
        }
        __syncthreads();
        int cl = tid & 31, kl4 = tid >> 5;
#pragma unroll
        for (int p = 0; p < 4; p++) {
            int kk = kl4 + p * 8;
            int k = k0 + kk;
            if (k < WVD) W1T[(size_t)k * H1 + c0 + cl] = tile[cl][kk];
        }
    } else if (blk < G_KA + G_W1T + G_EMB) {
        int lb = blk - G_KA - G_W1T;
        int wid = lb * 4 + (tid >> 6);
        int lane = tid & 63;
        int n = wid / 25, cp = wid - n * 25;
        int c0 = cp * 2;
        const float* xr = wv + (size_t)n * WVD;
        const float* wr0 = We + (size_t)c0 * WVD;
        const float* wr1 = wr0 + WVD;
        float a0 = 0.f, a1 = 0.f;
#pragma unroll
        for (int i = 0; i < 5; i++) {
            int k = i * 64 + lane;
            if (k < WVD) {
                float x = xr[k];
                a0 += x * wr0[k];
                a1 += x * wr1[k];
            }
        }
        for (int m = 32; m; m >>= 1) {
            a0 += __shfl_xor(a0, m, 64);
            a1 += __shfl_xor(a1, m, 64);
        }
        if (lane == 0) {
            float v0 = a0 + be[c0], v1 = a1 + be[c0 + 1];
            embs[n * EMB + c0] = v0;
            embs[n * EMB + c0 + 1] = v1;
            embsT[c0 * N + n] = v0;
            embsT[(c0 + 1) * N + n] = v1;
        }
    } else {
        int lb = blk - G_KA - G_W1T - G_EMB;
        int wid = lb * 4 + (tid >> 6);
        int lane = tid & 63;
        int t = wid / (N * SEG);
        int rem = wid - t * (N * SEG);
        int u = rem / SEG, seg = rem - u * SEG;
        const int* eut = eu + t * E;
        int e0 = seg * SEGLEN, e1 = e0 + SEGLEN, cnt = 0;
        for (int c = e0; c < e1; c += 64) {
            int e = c + lane;
            bool ok = (e < e1) && (eut[e] == u);
            cnt += __popcll(__ballot(ok));
        }
        if (lane == 0) segcnt[(t * N + u) * SEG + seg] = cnt;
    }
}

// ============ F2: partA-reduce | Wv GEMM | Ahat GEMM ============
__global__ __launch_bounds__(256) void k_f2(
        const float* partA, float* AbT,
        const float* wv, const float* W1T, float* Wp,
        const float* embsT, const float* RMbase, float* Ahat) {
    __shared__ float smemf[1800];
    int tid = threadIdx.x, blk = blockIdx.x;
    if (blk < G_ARED) {
        int cb = blk * 2048 + tid * 8;
        float4 s0 = {0, 0, 0, 0}, s1 = {0, 0, 0, 0};
#pragma unroll
        for (int ks = 0; ks < 8; ks++) {
            const float* p = partA + (size_t)ks * (H1 * B) + cb;
            float4 a = *(const float4*)p;
            float4 b4 = *(const float4*)(p + 4);
            s0.x += a.x; s0.y += a.y; s0.z += a.z; s0.w += a.w;
            s1.x += b4.x; s1.y += b4.y; s1.z += b4.z; s1.w += b4.w;
        }
        *(float4*)(AbT + cb) = s0;
        *(float4*)(AbT + cb + 4) = s1;
    } else if (blk < G_ARED + G_WV) {
        int lb = blk - G_ARED;
        int kh = lb >> 8;
        int rem = lb & 255;
        int c = (rem & 1) * 256 + tid;
        int n0 = (rem >> 1) * 8;
        int kb = kh * KH;
        float (*el)[8] = (float(*)[8])smemf;
        for (int idx = tid; idx < 8 * KH; idx += 256) {
            int j = idx / KH, k = idx - j * KH;
            el[k][j] = wv[(size_t)(n0 + j) * WVD + kb + k];
        }
        __syncthreads();
        float acc[8] = {};
#pragma unroll 5
        for (int k = 0; k < KH; k++) {
            float r = W1T[(size_t)(kb + k) * H1 + c];
            float4 e0 = *(const float4*)&el[k][0];
            float4 e1 = *(const float4*)&el[k][4];
            acc[0] += e0.x * r; acc[1] += e0.y * r;
            acc[2] += e0.z * r; acc[3] += e0.w * r;
            acc[4] += e1.x * r; acc[5] += e1.y * r;
            acc[6] += e1.z * r; acc[7] += e1.w * r;
        }
        float* wout = Wp + (size_t)kh * N * H1;
#pragma unroll
        for (int j = 0; j < 8; j++) wout[(size_t)(n0 + j) * H1 + c] = acc[j];
    } else {
        int lb = blk - G_ARED - G_WV;
        int t = lb / 416, r = lb % 416;
        int bx = r % 13, by = r / 13;
        const float* RM = RMbase + (size_t)t * EMB * RC;
        float* Ah = Ahat + (size_t)t * N * RC;
        int n0 = by * 32;
        float (*el)[36] = (float(*)[36])smemf;
        for (int idx = tid; idx < EMB * 32; idx += 256)
            el[idx >> 5][idx & 31] = embsT[(idx >> 5) * N + n0 + (idx & 31)];
        __syncthreads();
        int mi = bx * 256 + (tid & 63) * 4;
        int ni = (tid >> 6) * 8;
        if (mi < RC) {
            float acc[8][4] = {};
#pragma unroll 2
            for (int c = 0; c < EMB; c++) {
                float4 rm = *(const float4*)(RM + (size_t)c * RC + mi);
                float4 e0 = *(const float4*)&el[c][ni];
                float4 e1 = *(const float4*)&el[c][ni + 4];
                float ev[8] = {e0.x, e0.y, e0.z, e0.w, e1.x, e1.y, e1.z, e1.w};
#pragma unroll
                for (int j = 0; j < 8; j++) {
                    acc[j][0] += ev[j] * rm.x;
                    acc[j][1] += ev[j] * rm.y;
                    acc[j][2] += ev[j] * rm.z;
                    acc[j][3] += ev[j] * rm.w;
                }
            }
#pragma unroll
            for (int j = 0; j < 8; j++) {
                float4 o = {acc[j][0], acc[j][1], acc[j][2], acc[j][3]};
                *(float4*)(Ah + (size_t)(n0 + ni + j) * RC + mi) = o;
            }
        }
    }
}

// ============ F3: [blk<N] per-u build + weights (global Ahat) + inorm
//              [blk>=N] inputnet (4 n per block, W2 via L1 broadcast) ============
__global__ __launch_bounds__(256) void k_f3(
        const int* eu, const int* ev, const int* segcnt,
        const float* embs, const float* Ahat, float* wbuf, float* inorm,
        int* counts, int* sv,
        const float* AbT, const float* Wp, const float* b1,
        const float* W2, const float* b2, float* sT0) {
    __shared__ float smem[2560];   // 10 KB max over branches
    int tid = threadIdx.x;
    int blk = blockIdx.x;
    if (blk < N) {
        int u = blk;
        int* scnt2  = (int*)smem;              // [T*SEG] = 100
        int* soff2  = scnt2 + T * SEG;         // 100
        int* slist2 = soff2 + T * SEG;         // 100
        int* meta   = slist2 + T * SEG;        // [T*2]
        int* vl     = meta + 2 * T;            // [T*CAP] = 128
        float* rbuf = (float*)(vl + T * CAP);  // 256
        int w = tid >> 6, lane = tid & 63;
        if (tid < T * SEG) {
            int t = tid / SEG, s2 = tid - t * SEG;
            scnt2[tid] = segcnt[((size_t)(t * N + u)) * SEG + s2];
        }
        __syncthreads();
        if (tid < T) {
            int t = tid;
            int off = 0, nn = 0;
            for (int j = 0; j < SEG; j++) {
                int c = scnt2[t * SEG + j];
                soff2[t * SEG + j] = off;
                off += c;
                if (c > 0) slist2[t * SEG + nn++] = j;
            }
            meta[t * 2] = nn;
            meta[t * 2 + 1] = off;
            counts[t * N + u] = off;
        }
        __syncthreads();
        // scatter: 2 waves per type, round-robin nonzero segments
        {
            int t = w >> 1, sub = w & 1;
            int nnz = meta[t * 2];
            const int* eut = eu + t * E;
            const int* evt = ev + t * E;
            size_t svbase = (size_t)(t * N + u) * CAP;
            for (int idx = sub; idx < nnz; idx += 2) {
                int seg = slist2[t * SEG + idx];
                int sbase = soff2[t * SEG + seg];
                int e0 = seg * SEGLEN, e1 = e0 + SEGLEN, c2 = 0;
                for (int c = e0; c < e1; c += 64) {
                    int e = c + lane;
                    bool ok = (e < e1) && (eut[e] == u);
                    unsigned long long m = __ballot(ok);
                    if (ok) {
                        int rank = __popcll(m & ((1ull << lane) - 1));
                        int pos = sbase + c2 + rank;
                        vl[t * CAP + pos] = evt[e];
                        sv[svbase + pos] = evt[e];
                    }
                    c2 += __popcll(m);
                }
            }
        }
        __syncthreads();
        // weights: direct coalesced global Ahat reads, 2-edge ILP
        int k = lane;
        float ssq = 0.f;
        for (int t = 0; t < T; t++) {
            int cnt = meta[t * 2 + 1];
            const float* Arow = Ahat + (size_t)(t * N + u) * RC;
            size_t wbase = (size_t)(t * N + u) * CAP;
            for (int i = w; i < cnt; i += 8) {
                int i2 = i + 4;
                bool h2 = i2 < cnt;
                int v0 = vl[t * CAP + i];
                int v1 = h2 ? vl[t * CAP + i2] : v0;
                const float* vr0 = embs + v0 * EMB;
                const float* vr1 = embs + v1 * EMB;
                float a0 = 0.f, a1 = 0.f;
#pragma unroll 10
                for (int d = 0; d < EMB; d++) {
                    float al = Arow[d * 64 + k];
                    a0 += vr0[d] * al;
                    a1 += vr1[d] * al;
                }
                wbuf[(wbase + i) * 64 + k] = a0;
                ssq += a0 * a0;
                if (h2) {
                    wbuf[(wbase + i2) * 64 + k] = a1;
                    ssq += a1 * a1;
                }
            }
        }
        __syncthreads();
        rbuf[w * 64 + k] = ssq;
        __syncthreads();
        if (tid < 64) {
            float tot = rbuf[tid] + rbuf[64 + tid] + rbuf[128 + tid] + rbuf[192 + tid];
            tot += __shfl_xor(tot, 1, 64);
            tot += __shfl_xor(tot, 2, 64);
            tot += __shfl_xor(tot, 4, 64);
            int ki = tid >> 3, kj = tid & 7;
            if (kj == 0) {
                float nv = sqrtf(tot);
                if (nv == 0.f) nv = 1.f;
                inorm[u * ND + ki] = 1.0f / nv;
            }
        }
    } else {
        // inputnet: 4 n per block; W2 read via wave-broadcast global loads
        int n0 = (blk - N) * 4;
        float* wvs  = smem;            // 512
        float* part = smem + 512;      // 2048
        int b = tid & 31, s = tid >> 5;
        int ki2 = tid >> 5, b2i = tid & 31;
        for (int nn = 0; nn < 4; nn++) {
            int n = n0 + nn;
            __syncthreads();
            for (int idx = tid; idx < H1; idx += 256)
                wvs[idx] = Wp[(size_t)n * H1 + idx]
                         + Wp[(size_t)N * H1 + (size_t)n * H1 + idx] + b1[idx];
            __syncthreads();
            float acc[8] = {};
            for (int i = 0; i < 64; i++) {
                int c = s * 64 + i;
                float tv = fmaxf(AbT[c * 32 + b] + wvs[c], 0.f);
#pragma unroll
                for (int ki = 0; ki < 8; ki++) acc[ki] += tv * W2[ki * H1 + c];
            }
#pragma unroll
            for (int ki = 0; ki < 8; ki++) part[s * 256 + ki * 32 + b] = acc[ki];
            __syncthreads();
            float tot = b2[ki2];
#pragma unroll
            for (int s2 = 0; s2 < 8; s2++) tot += part[s2 * 256 + ki2 * 32 + b2i];
            sT0[(size_t)n * 256 + tid] = tot;
        }
    }
}

// ============ propagation step: 2-edge-unrolled SpMM (inline inorm) + GRU ============
__global__ __launch_bounds__(256) void k_step(
        const int* counts, const int* sv,
        const float* wbuf, const float* inorm, const float* sT, int s,
        const float* W_ih, const float* W_hh, const float* b_ih, const float* b_hh,
        const float* Wo1, const float* bo1, const float* Wo2, const float* bo2,
        float* sOut, float* out, int last) {
    __shared__ float xs[256], hs[256], hfin[256];
    __shared__ float wih[192], whh[192];
    __shared__ float w1s[160], b1s[20], w2s[20];
    __shared__ float res[8][33];
    int tid = threadIdx.x;
    int u = blockIdx.x;
    int ki = tid >> 5, b = tid & 31;
    if (tid < 192) { wih[tid] = W_ih[tid]; whh[tid] = W_hh[tid]; }
    if (last) {
        if (tid < 160) w1s[tid] = Wo1[tid];
        if (tid < 20) { b1s[tid] = bo1[tid]; w2s[tid] = Wo2[tid]; }
    }
    const float* sIn = sT + (size_t)s * NDIM * B;
    float hown = sIn[((size_t)u * 8 + ki) * B + b];
    float acc = 0.f;
    for (int t = 0; t < T; t++) {
        int row = t * N + u;
        int cnt = counts[row];
        size_t base = (size_t)row * CAP;
        int i = 0;
        for (; i + 1 < cnt; i += 2) {
            size_t s0 = base + i, s1 = base + i + 1;
            int v0 = sv[s0], v1 = sv[s1];
            const float* wp0 = wbuf + s0 * 64 + ki * 8;
            const float* wp1 = wbuf + s1 * 64 + ki * 8;
            float4 wa0 = *(const float4*)wp0;
            float4 wb0 = *(const float4*)(wp0 + 4);
            float4 wa1 = *(const float4*)wp1;
            float4 wb1 = *(const float4*)(wp1 + 4);
            const float* ip0 = inorm + v0 * ND;
            const float* ip1 = inorm + v1 * ND;
            const float* hp0 = sIn + (size_t)v0 * 256 + b;
            const float* hp1 = sIn + (size_t)v1 * 256 + b;
            acc += (wa0.x * ip0[0]) * hp0[0]   + (wa0.y * ip0[1]) * hp0[32]
                 + (wa0.z * ip0[2]) * hp0[64]  + (wa0.w * ip0[3]) * hp0[96]
                 + (wb0.x * ip0[4]) * hp0[128] + (wb0.y * ip0[5]) * hp0[160]
                 + (wb0.z * ip0[6]) * hp0[192] + (wb0.w * ip0[7]) * hp0[224];
            acc += (wa1.x * ip1[0]) * hp1[0]   + (wa1.y * ip1[1]) * hp1[32]
                 + (wa1.z * ip1[2]) * hp1[64]  + (wa1.w * ip1[3]) * hp1[96]
                 + (wb1.x * ip1[4]) * hp1[128] + (wb1.y * ip1[5]) * hp1[160]
                 + (wb1.z * ip1[6]) * hp1[192] + (wb1.w * ip1[7]) * hp1[224];
        }
        if (i < cnt) {
            size_t s0 = base + i;
            int v0 = sv[s0];
            const float* wp0 = wbuf + s0 * 64 + ki * 8;
            float4 wa0 = *(const float4*)wp0;
            float4 wb0 = *(const float4*)(wp0 + 4);
            const float* ip0 = inorm + v0 * ND;
            const float* hp0 = sIn + (size_t)v0 * 256 + b;
            acc += (wa0.x * ip0[0]) * hp0[0]   + (wa0.y * ip0[1]) * hp0[32]
                 + (wa0.z * ip0[2]) * hp0[64]  + (wa0.w * ip0[3]) * hp0[96]
                 + (wb0.x * ip0[4]) * hp0[128] + (wb0.y * ip0[5]) * hp0[160]
                 + (wb0.z * ip0[6]) * hp0[192] + (wb0.w * ip0[7]) * hp0[224];
        }
    }
    float xv = tanhf(acc);
    xs[ki * 32 + b] = xv;
    hs[ki * 32 + b] = hown;
    __syncthreads();
    float gr = b_ih[ki], gz = b_ih[8 + ki], gn = b_ih[16 + ki];
    float hr = b_hh[ki], hz = b_hh[8 + ki], hn = b_hh[16 + ki];
#pragma unroll
    for (int j = 0; j < 8; j++) {
        float xj = xs[j * 32 + b], hj = hs[j * 32 + b];
        gr += wih[ki * 8 + j] * xj;
        gz += wih[(8 + ki) * 8 + j] * xj;
        gn += wih[(16 + ki) * 8 + j] * xj;
        hr += whh[ki * 8 + j] * hj;
        hz += whh[(8 + ki) * 8 + j] * hj;
        hn += whh[(16 + ki) * 8 + j] * hj;
    }
    float r = 1.f / (1.f + expf(-(gr + hr)));
    float z = 1.f / (1.f + expf(-(gz + hz)));
    float nn = tanhf(gn + r * hn);
    float hnew = (1.f - z) * nn + z * hown;
    if (!last) {
        sOut[((size_t)u * 8 + ki) * B + b] = hnew;
        return;
    }
    hfin[ki * 32 + b] = hnew;
    __syncthreads();
    int s6 = tid >> 5, bb = tid & 31;
    if (s6 < 6) {
        float x[8];
#pragma unroll
        for (int kk = 0; kk < 8; kk++)
            x[kk] = (s6 < STEPS)
                ? sT[((size_t)s6 * NDIM + u * 8 + kk) * B + bb]
                : hfin[kk * 32 + bb];
        float accv = bo2[0];
#pragma unroll
        for (int j = 0; j < 20; j++) {
            float h = b1s[j];
#pragma unroll
            for (int kk = 0; kk < 8; kk++) h += w1s[j * 8 + kk] * x[kk];
            h = fmaxf(h, 0.f);
            accv += w2s[j] * h;
        }
        res[s6][bb] = accv;
    }
    __syncthreads();
    if (tid < 192) {
        int b_w = tid / 6, s_w = tid - b_w * 6;
        out[(size_t)b_w * ((STEPS + 1) * N) + u * (STEPS + 1) + s_w] = res[s_w][b_w];
    }
}

extern "C" void kernel_launch(void* const* d_in, const int* in_sizes, int n_in,
                              void* d_out, int out_size, void* d_ws, size_t ws_size,
                              hipStream_t stream) {
    const float* inputs   = (const float*)d_in[0];
    const float* wordvecs = (const float*)d_in[1];
    const int*   edge_u   = (const int*)d_in[2];
    const int*   edge_v   = (const int*)d_in[3];
    const float* W_in1 = (const float*)d_in[6];
    const float* b_in1 = (const float*)d_in[7];
    const float* W_in2 = (const float*)d_in[8];
    const float* b_in2 = (const float*)d_in[9];
    const float* W_emb = (const float*)d_in[10];
    const float* b_emb = (const float*)d_in[11];
    const float* rel_mats = (const float*)d_in[12];
    const float* W_ih = (const float*)d_in[13];
    const float* W_hh = (const float*)d_in[14];
    const float* b_ih = (const float*)d_in[15];
    const float* b_hh = (const float*)d_in[16];
    const float* W_o1 = (const float*)d_in[17];
    const float* b_o1 = (const float*)d_in[18];
    const float* W_o2 = (const float*)d_in[19];
    const float* b_o2 = (const float*)d_in[20];
    float* out = (float*)d_out;

    char* ws = (char*)d_ws;
    size_t off = 0;
    auto alloc = [&](size_t bytes) -> void* {
        void* p = ws + off;
        off = (off + bytes + 255) & ~(size_t)255;
        return p;
    };
    int* segcnt    = (int*)alloc((size_t)T * N * SEG * 4);
    int* counts    = (int*)alloc(2048 * 4);
    int* sv        = (int*)alloc((size_t)T * N * CAP * 4);
    float* inorm   = (float*)alloc((size_t)NDIM * 4);
    float* partA   = (float*)alloc((size_t)8 * H1 * B * 4);
    float* AbT     = (float*)alloc((size_t)H1 * B * 4);
    float* W1T     = (float*)alloc((size_t)WVD * H1 * 4);
    float* Wp      = (float*)alloc((size_t)2 * N * H1 * 4);
    float* embs    = (float*)alloc((size_t)N * EMB * 4);
    float* embsT   = (float*)alloc((size_t)EMB * N * 4);
    float* Ahat    = (float*)alloc((size_t)T * N * RC * 4);
    float* wbuf    = (float*)alloc((size_t)T * N * CAP * 64 * 4);
    float* sT      = (float*)alloc((size_t)(STEPS + 1) * NDIM * B * 4);

    k_f1<<<F1_TOT, 256, 0, stream>>>(edge_u, segcnt, inputs, W_in1, partA, W1T,
                                     wordvecs, W_emb, b_emb, embs, embsT);
    k_f2<<<F2_TOT, 256, 0, stream>>>(partA, AbT, wordvecs, W1T, Wp,
                                     embsT, rel_mats, Ahat);
    k_f3<<<F3_TOT, 256, 0, stream>>>(edge_u, edge_v, segcnt,
                                     embs, Ahat, wbuf, inorm, counts, sv,
                                     AbT, Wp, b_in1, W_in2, b_in2, sT);

    for (int s = 0; s < STEPS; s++) {
        int last = (s == STEPS - 1) ? 1 : 0;
        k_step<<<N, 256, 0, stream>>>(counts, sv, wbuf, inorm, sT, s,
                                      W_ih, W_hh, b_ih, b_hh,
                                      W_o1, b_o1, W_o2, b_o2,
                                      sT + (size_t)(s + 1) * NDIM * B, out, last);
    }
}

// Round 20
// 254.037 us; speedup vs baseline: 1.0449x; 1.0342x over previous
//
#include <hip/hip_runtime.h>
#include <math.h>

constexpr int B = 32, N = 1024, ND = 8, FEAT = 2048, WVD = 300;
constexpr int E = 20000, T = 2, STEPS = 5;
constexpr int NDIM = N * ND;            // 8192
constexpr int H1 = 512;
constexpr int W1C = FEAT + WVD;         // 2348
constexpr int EMB = 50;
constexpr int RC = EMB * ND * ND;       // 3200
constexpr int KH = 150;                 // Wv k-split half
constexpr int CAP = 64;                 // fixed row capacity (P(row>64)~1e-20)
constexpr int SEG = 50;                 // fine segments for skip-scan
constexpr int SEGLEN = E / SEG;         // 400 (not mult of 64 — guard)

// k_f1 sections
constexpr int G_KA   = 512;
constexpr int G_W1T  = 16 * 10;
constexpr int G_EMB  = N * 25 / 4;         // 6400
constexpr int G_SEGH = T * N * SEG / 4;    // 25600
constexpr int F1_TOT = G_KA + G_W1T + G_EMB + G_SEGH;

// k_f2 sections
constexpr int G_ARED = 8;
constexpr int G_WV   = 512;
constexpr int G_AHAT = 13 * 32 * T;        // 832
constexpr int F2_TOT = G_ARED + G_WV + G_AHAT;

// k_f3 sections
constexpr int G_INP  = N / 4;              // 256 (4 n per block)
constexpr int F3_TOT = N + G_INP;

// ============ F1: k_A GEMM | W1-transpose | embs(+embsT) | seghist(50) ============
__global__ __launch_bounds__(256) void k_f1(
        const int* eu, int* segcnt,
        const float* inp, const float* W1, float* partA, float* W1T,
        const float* wv, const float* We, const float* be,
        float* embs, float* embsT) {
    __shared__ float smem[8 * 260];
    int tid = threadIdx.x;
    int blk = blockIdx.x;
    if (blk < G_KA) {
        int c = tid & 7, b = tid >> 3;
        int c0 = (blk & 63) * 8;
        int ks = blk >> 6;
        int kt = ks * 256;
        {
            int r = tid >> 5, cb = (tid & 31) * 8;
            const float* src = W1 + (size_t)(c0 + r) * W1C + kt + cb;
            float4 a0 = *(const float4*)src;
            float4 a1 = *(const float4*)(src + 4);
            *(float4*)&smem[r * 260 + cb] = a0;
            *(float4*)&smem[r * 260 + cb + 4] = a1;
        }
        __syncthreads();
        const float* xr = inp + (size_t)b * FEAT + kt;
        float acc = 0.f;
#pragma unroll 8
        for (int k4 = 0; k4 < 64; k4++) {
            float4 x = *(const float4*)(xr + k4 * 4);
            float4 w = *(const float4*)&smem[c * 260 + k4 * 4];
            acc += x.x * w.x + x.y * w.y + x.z * w.z + x.w * w.w;
        }
        partA[(size_t)ks * (H1 * B) + (c0 + c) * B + b] = acc;
    } else if (blk < G_KA + G_W1T) {
        int lb = blk - G_KA;
        int c0 = (lb % 16) * 32, k0 = (lb / 16) * 32;
        float (*tile)[33] = (float(*)[33])smem;
        int kl = tid & 31, cl4 = tid >> 5;
#pragma unroll
        for (int p = 0; p < 4; p++) {
            int c = cl4 + p * 8;
            int k = k0 + kl;
            if (k < WVD) tile[c][kl] = W1[(size_t)(c0 + c) * W1C + FEAT + k];
        }
        __syncthreads();
        int cl = tid & 31, kl4 = tid >> 5;
#pragma unroll
        for (int p = 0; p < 4; p++) {
            int kk = kl4 + p * 8;
            int k = k0 + kk;
            if (k < WVD) W1T[(size_t)k * H1 + c0 + cl] = tile[cl][kk];
        }
    } else if (blk < G_KA + G_W1T + G_EMB) {
        int lb = blk - G_KA - G_W1T;
        int wid = lb * 4 + (tid >> 6);
        int lane = tid & 63;
        int n = wid / 25, cp = wid - n * 25;
        int c0 = cp * 2;
        const float* xr = wv + (size_t)n * WVD;
        const float* wr0 = We + (size_t)c0 * WVD;
        const float* wr1 = wr0 + WVD;
        float a0 = 0.f, a1 = 0.f;
#pragma unroll
        for (int i = 0; i < 5; i++) {
            int k = i * 64 + lane;
            if (k < WVD) {
                float x = xr[k];
                a0 += x * wr0[k];
                a1 += x * wr1[k];
            }
        }
        for (int m = 32; m; m >>= 1) {
            a0 += __shfl_xor(a0, m, 64);
            a1 += __shfl_xor(a1, m, 64);
        }
        if (lane == 0) {
            float v0 = a0 + be[c0], v1 = a1 + be[c0 + 1];
            embs[n * EMB + c0] = v0;
            embs[n * EMB + c0 + 1] = v1;
            embsT[c0 * N + n] = v0;
            embsT[(c0 + 1) * N + n] = v1;
        }
    } else {
        int lb = blk - G_KA - G_W1T - G_EMB;
        int wid = lb * 4 + (tid >> 6);
        int lane = tid & 63;
        int t = wid / (N * SEG);
        int rem = wid - t * (N * SEG);
        int u = rem / SEG, seg = rem - u * SEG;
        const int* eut = eu + t * E;
        int e0 = seg * SEGLEN, e1 = e0 + SEGLEN, cnt = 0;
        for (int c = e0; c < e1; c += 64) {
            int e = c + lane;
            bool ok = (e < e1) && (eut[e] == u);
            cnt += __popcll(__ballot(ok));
        }
        if (lane == 0) segcnt[(t * N + u) * SEG + seg] = cnt;
    }
}

// ============ F2: partA-reduce | Wv GEMM | Ahat GEMM ============
__global__ __launch_bounds__(256) void k_f2(
        const float* partA, float* AbT,
        const float* wv, const float* W1T, float* Wp,
        const float* embsT, const float* RMbase, float* Ahat) {
    __shared__ float smemf[1800];
    int tid = threadIdx.x, blk = blockIdx.x;
    if (blk < G_ARED) {
        int cb = blk * 2048 + tid * 8;
        float4 s0 = {0, 0, 0, 0}, s1 = {0, 0, 0, 0};
#pragma unroll
        for (int ks = 0; ks < 8; ks++) {
            const float* p = partA + (size_t)ks * (H1 * B) + cb;
            float4 a = *(const float4*)p;
            float4 b4 = *(const float4*)(p + 4);
            s0.x += a.x; s0.y += a.y; s0.z += a.z; s0.w += a.w;
            s1.x += b4.x; s1.y += b4.y; s1.z += b4.z; s1.w += b4.w;
        }
        *(float4*)(AbT + cb) = s0;
        *(float4*)(AbT + cb + 4) = s1;
    } else if (blk < G_ARED + G_WV) {
        int lb = blk - G_ARED;
        int kh = lb >> 8;
        int rem = lb & 255;
        int c = (rem & 1) * 256 + tid;
        int n0 = (rem >> 1) * 8;
        int kb = kh * KH;
        float (*el)[8] = (float(*)[8])smemf;
        for (int idx = tid; idx < 8 * KH; idx += 256) {
            int j = idx / KH, k = idx - j * KH;
            el[k][j] = wv[(size_t)(n0 + j) * WVD + kb + k];
        }
        __syncthreads();
        float acc[8] = {};
#pragma unroll 5
        for (int k = 0; k < KH; k++) {
            float r = W1T[(size_t)(kb + k) * H1 + c];
            float4 e0 = *(const float4*)&el[k][0];
            float4 e1 = *(const float4*)&el[k][4];
            acc[0] += e0.x * r; acc[1] += e0.y * r;
            acc[2] += e0.z * r; acc[3] += e0.w * r;
            acc[4] += e1.x * r; acc[5] += e1.y * r;
            acc[6] += e1.z * r; acc[7] += e1.w * r;
        }
        float* wout = Wp + (size_t)kh * N * H1;
#pragma unroll
        for (int j = 0; j < 8; j++) wout[(size_t)(n0 + j) * H1 + c] = acc[j];
    } else {
        int lb = blk - G_ARED - G_WV;
        int t = lb / 416, r = lb % 416;
        int bx = r % 13, by = r / 13;
        const float* RM = RMbase + (size_t)t * EMB * RC;
        float* Ah = Ahat + (size_t)t * N * RC;
        int n0 = by * 32;
        float (*el)[36] = (float(*)[36])smemf;
        for (int idx = tid; idx < EMB * 32; idx += 256)
            el[idx >> 5][idx & 31] = embsT[(idx >> 5) * N + n0 + (idx & 31)];
        __syncthreads();
        int mi = bx * 256 + (tid & 63) * 4;
        int ni = (tid >> 6) * 8;
        if (mi < RC) {
            float acc[8][4] = {};
#pragma unroll 2
            for (int c = 0; c < EMB; c++) {
                float4 rm = *(const float4*)(RM + (size_t)c * RC + mi);
                float4 e0 = *(const float4*)&el[c][ni];
                float4 e1 = *(const float4*)&el[c][ni + 4];
                float ev[8] = {e0.x, e0.y, e0.z, e0.w, e1.x, e1.y, e1.z, e1.w};
#pragma unroll
                for (int j = 0; j < 8; j++) {
                    acc[j][0] += ev[j] * rm.x;
                    acc[j][1] += ev[j] * rm.y;
                    acc[j][2] += ev[j] * rm.z;
                    acc[j][3] += ev[j] * rm.w;
                }
            }
#pragma unroll
            for (int j = 0; j < 8; j++) {
                float4 o = {acc[j][0], acc[j][1], acc[j][2], acc[j][3]};
                *(float4*)(Ah + (size_t)(n0 + ni + j) * RC + mi) = o;
            }
        }
    }
}

// ============ F3: [blk<N] skip-scan build + LDS-staged weights + norms
//              [blk>=N] slim inputnet (no W2 LDS) — kernel LDS = 14.6 KB ============
__global__ __launch_bounds__(256) void k_f3(
        const int* eu, const int* ev, const int* segcnt,
        const float* embs, const float* Ahat, float* wbuf, float* inorm,
        int* counts, int* sv,
        const float* AbT, const float* Wp, const float* b1,
        const float* W2, const float* b2, float* sT0) {
    __shared__ float smem[3648];   // 14.6 KB max over branches
    int tid = threadIdx.x;
    int blk = blockIdx.x;
    if (blk < N) {
        int u = blk;
        float* AL   = smem;                       // [3200]
        int* vl     = (int*)(smem + 3200);        // [T*CAP] = 128
        int* scnt   = vl + T * CAP;               // [T*SEG] = 100
        int* soff   = scnt + T * SEG;             // 100
        int* slist  = soff + T * SEG;             // 100
        int* smeta  = slist + T * SEG;            // nnz[T], ctot[T]
        int w = tid >> 6, lane = tid & 63;
        if (tid < T * SEG) {
            int t = tid / SEG, s = tid - t * SEG;
            scnt[tid] = segcnt[((size_t)t * N + u) * SEG + s];
        }
        __syncthreads();
        if (w < T && lane == 0) {
            int off = 0, nn = 0;
            for (int j = 0; j < SEG; j++) {
                int c = scnt[w * SEG + j];
                soff[w * SEG + j] = off;
                off += c;
                if (c > 0) slist[w * SEG + nn++] = j;
            }
            smeta[w] = nn;          // nnz
            smeta[T + w] = off;     // total count
            counts[w * N + u] = off;
        }
        __syncthreads();
        // scatter: 2 waves per row, round-robin over nonzero segments
        {
            int myrow = w >> 1, sub = w & 1;
            int row = myrow * N + u;
            const int* eut = eu + myrow * E;
            const int* evt = ev + myrow * E;
            int nnz = smeta[myrow];
            for (int idx = sub; idx < nnz; idx += 2) {
                int seg = slist[myrow * SEG + idx];
                int base = soff[myrow * SEG + seg];
                int e0 = seg * SEGLEN, e1 = e0 + SEGLEN, cnt = 0;
                for (int c = e0; c < e1; c += 64) {
                    int e = c + lane;
                    bool ok = (e < e1) && (eut[e] == u);
                    unsigned long long m = __ballot(ok);
                    if (ok) {
                        int rank = __popcll(m & ((1ull << lane) - 1));
                        int pos = base + cnt + rank;
                        vl[myrow * CAP + pos] = evt[e];
                        sv[(size_t)row * CAP + pos] = evt[e];
                    }
                    cnt += __popcll(m);
                }
            }
        }
        __syncthreads();
        int cnts[T];
#pragma unroll
        for (int t = 0; t < T; t++) cnts[t] = smeta[T + t];
        // edge weights + fused norms (float4-staged panel)
        int k = lane;
        float ssq = 0.f;
        for (int t = 0; t < T; t++) {
            __syncthreads();
            {
                const float4* asrc = (const float4*)(Ahat + ((size_t)t * N + u) * RC);
                float4* adst = (float4*)AL;
                for (int idx = tid; idx < RC / 4; idx += 256)
                    adst[idx] = asrc[idx];
            }
            __syncthreads();
            int cnt = cnts[t];
            size_t base = (size_t)(t * N + u) * CAP;
            for (int i = w; i < cnt; i += 4) {
                int v = vl[t * CAP + i];
                const float* vr = embs + v * EMB;
                float acc = 0.f;
#pragma unroll 10
                for (int d = 0; d < EMB; d++) acc += vr[d] * AL[d * 64 + k];
                wbuf[(base + i) * 64 + k] = acc;
                ssq += acc * acc;
            }
        }
        __syncthreads();
        AL[w * 64 + k] = ssq;
        __syncthreads();
        if (tid < 64) {
            float tot = AL[tid] + AL[64 + tid] + AL[128 + tid] + AL[192 + tid];
            tot += __shfl_xor(tot, 1, 64);
            tot += __shfl_xor(tot, 2, 64);
            tot += __shfl_xor(tot, 4, 64);
            int ki = tid >> 3, kj = tid & 7;
            if (kj == 0) {
                float nv = sqrtf(tot);
                if (nv == 0.f) nv = 1.f;
                inorm[u * ND + ki] = 1.0f / nv;
            }
        }
    } else {
        // slim inputnet: 4 n per block; W2 via wave-uniform global broadcast
        int n0 = (blk - N) * 4;
        float* wvs  = smem;            // 512
        float* part = smem + 512;      // 2048
        int b = tid & 31, s = tid >> 5;
        int ki2 = tid >> 5, b2i = tid & 31;
        for (int nn = 0; nn < 4; nn++) {
            int n = n0 + nn;
            __syncthreads();
            for (int idx = tid; idx < H1; idx += 256)
                wvs[idx] = Wp[(size_t)n * H1 + idx]
                         + Wp[(size_t)N * H1 + (size_t)n * H1 + idx] + b1[idx];
            __syncthreads();
            float acc[8] = {};
            for (int i = 0; i < 64; i++) {
                int c = s * 64 + i;
                float tv = fmaxf(AbT[c * 32 + b] + wvs[c], 0.f);
#pragma unroll
                for (int ki = 0; ki < 8; ki++) acc[ki] += tv * W2[ki * H1 + c];
            }
#pragma unroll
            for (int ki = 0; ki < 8; ki++) part[s * 256 + ki * 32 + b] = acc[ki];
            __syncthreads();
            float tot = b2[ki2];
#pragma unroll
            for (int s2 = 0; s2 < 8; s2++) tot += part[s2 * 256 + ki2 * 32 + b2i];
            sT0[(size_t)n * 256 + tid] = tot;
        }
    }
}

// ============ propagation step: 2-edge-unrolled SpMM (inline inorm) + GRU ============
__global__ __launch_bounds__(256) void k_step(
        const int* counts, const int* sv,
        const float* wbuf, const float* inorm, const float* sT, int s,
        const float* W_ih, const float* W_hh, const float* b_ih, const float* b_hh,
        const float* Wo1, const float* bo1, const float* Wo2, const float* bo2,
        float* sOut, float* out, int last) {
    __shared__ float xs[256], hs[256], hfin[256];
    __shared__ float wih[192], whh[192];
    __shared__ float w1s[160], b1s[20], w2s[20];
    __shared__ float res[8][33];
    int tid = threadIdx.x;
    int u = blockIdx.x;
    int ki = tid >> 5, b = tid & 31;
    if (tid < 192) { wih[tid] = W_ih[tid]; whh[tid] = W_hh[tid]; }
    if (last) {
        if (tid < 160) w1s[tid] = Wo1[tid];
        if (tid < 20) { b1s[tid] = bo1[tid]; w2s[tid] = Wo2[tid]; }
    }
    const float* sIn = sT + (size_t)s * NDIM * B;
    float hown = sIn[((size_t)u * 8 + ki) * B + b];
    float acc = 0.f;
    for (int t = 0; t < T; t++) {
        int row = t * N + u;
        int cnt = counts[row];
        size_t base = (size_t)row * CAP;
        int i = 0;
        for (; i + 1 < cnt; i += 2) {
            size_t s0 = base + i, s1 = base + i + 1;
            int v0 = sv[s0], v1 = sv[s1];
            const float* wp0 = wbuf + s0 * 64 + ki * 8;
            const float* wp1 = wbuf + s1 * 64 + ki * 8;
            float4 wa0 = *(const float4*)wp0;
            float4 wb0 = *(const float4*)(wp0 + 4);
            float4 wa1 = *(const float4*)wp1;
            float4 wb1 = *(const float4*)(wp1 + 4);
            const float* ip0 = inorm + v0 * ND;
            const float* ip1 = inorm + v1 * ND;
            const float* hp0 = sIn + (size_t)v0 * 256 + b;
            const float* hp1 = sIn + (size_t)v1 * 256 + b;
            acc += (wa0.x * ip0[0]) * hp0[0]   + (wa0.y * ip0[1]) * hp0[32]
                 + (wa0.z * ip0[2]) * hp0[64]  + (wa0.w * ip0[3]) * hp0[96]
                 + (wb0.x * ip0[4]) * hp0[128] + (wb0.y * ip0[5]) * hp0[160]
                 + (wb0.z * ip0[6]) * hp0[192] + (wb0.w * ip0[7]) * hp0[224];
            acc += (wa1.x * ip1[0]) * hp1[0]   + (wa1.y * ip1[1]) * hp1[32]
                 + (wa1.z * ip1[2]) * hp1[64]  + (wa1.w * ip1[3]) * hp1[96]
                 + (wb1.x * ip1[4]) * hp1[128] + (wb1.y * ip1[5]) * hp1[160]
                 + (wb1.z * ip1[6]) * hp1[192] + (wb1.w * ip1[7]) * hp1[224];
        }
        if (i < cnt) {
            size_t s0 = base + i;
            int v0 = sv[s0];
            const float* wp0 = wbuf + s0 * 64 + ki * 8;
            float4 wa0 = *(const float4*)wp0;
            float4 wb0 = *(const float4*)(wp0 + 4);
            const float* ip0 = inorm + v0 * ND;
            const float* hp0 = sIn + (size_t)v0 * 256 + b;
            acc += (wa0.x * ip0[0]) * hp0[0]   + (wa0.y * ip0[1]) * hp0[32]
                 + (wa0.z * ip0[2]) * hp0[64]  + (wa0.w * ip0[3]) * hp0[96]
                 + (wb0.x * ip0[4]) * hp0[128] + (wb0.y * ip0[5]) * hp0[160]
                 + (wb0.z * ip0[6]) * hp0[192] + (wb0.w * ip0[7]) * hp0[224];
        }
    }
    float xv = tanhf(acc);
    xs[ki * 32 + b] = xv;
    hs[ki * 32 + b] = hown;
    __syncthreads();
    float gr = b_ih[ki], gz = b_ih[8 + ki], gn = b_ih[16 + ki];
    float hr = b_hh[ki], hz = b_hh[8 + ki], hn = b_hh[16 + ki];
#pragma unroll
    for (int j = 0; j < 8; j++) {
        float xj = xs[j * 32 + b], hj = hs[j * 32 + b];
        gr += wih[ki * 8 + j] * xj;
        gz += wih[(8 + ki) * 8 + j] * xj;
        gn += wih[(16 + ki) * 8 + j] * xj;
        hr += whh[ki * 8 + j] * hj;
        hz += whh[(8 + ki) * 8 + j] * hj;
        hn += whh[(16 + ki) * 8 + j] * hj;
    }
    float r = 1.f / (1.f + expf(-(gr + hr)));
    float z = 1.f / (1.f + expf(-(gz + hz)));
    float nn = tanhf(gn + r * hn);
    float hnew = (1.f - z) * nn + z * hown;
    if (!last) {
        sOut[((size_t)u * 8 + ki) * B + b] = hnew;
        return;
    }
    hfin[ki * 32 + b] = hnew;
    __syncthreads();
    int s6 = tid >> 5, bb = tid & 31;
    if (s6 < 6) {
        float x[8];
#pragma unroll
        for (int kk = 0; kk < 8; kk++)
            x[kk] = (s6 < STEPS)
                ? sT[((size_t)s6 * NDIM + u * 8 + kk) * B + bb]
                : hfin[kk * 32 + bb];
        float accv = bo2[0];
#pragma unroll
        for (int j = 0; j < 20; j++) {
            float h = b1s[j];
#pragma unroll
            for (int kk = 0; kk < 8; kk++) h += w1s[j * 8 + kk] * x[kk];
            h = fmaxf(h, 0.f);
            accv += w2s[j] * h;
        }
        res[s6][bb] = accv;
    }
    __syncthreads();
    if (tid < 192) {
        int b_w = tid / 6, s_w = tid - b_w * 6;
        out[(size_t)b_w * ((STEPS + 1) * N) + u * (STEPS + 1) + s_w] = res[s_w][b_w];
    }
}

extern "C" void kernel_launch(void* const* d_in, const int* in_sizes, int n_in,
                              void* d_out, int out_size, void* d_ws, size_t ws_size,
                              hipStream_t stream) {
    const float* inputs   = (const float*)d_in[0];
    const float* wordvecs = (const float*)d_in[1];
    const int*   edge_u   = (const int*)d_in[2];
    const int*   edge_v   = (const int*)d_in[3];
    const float* W_in1 = (const float*)d_in[6];
    const float* b_in1 = (const float*)d_in[7];
    const float* W_in2 = (const float*)d_in[8];
    const float* b_in2 = (const float*)d_in[9];
    const float* W_emb = (const float*)d_in[10];
    const float* b_emb = (const float*)d_in[11];
    const float* rel_mats = (const float*)d_in[12];
    const float* W_ih = (const float*)d_in[13];
    const float* W_hh = (const float*)d_in[14];
    const float* b_ih = (const float*)d_in[15];
    const float* b_hh = (const float*)d_in[16];
    const float* W_o1 = (const float*)d_in[17];
    const float* b_o1 = (const float*)d_in[18];
    const float* W_o2 = (const float*)d_in[19];
    const float* b_o2 = (const float*)d_in[20];
    float* out = (float*)d_out;

    char* ws = (char*)d_ws;
    size_t off = 0;
    auto alloc = [&](size_t bytes) -> void* {
        void* p = ws + off;
        off = (off + bytes + 255) & ~(size_t)255;
        return p;
    };
    int* segcnt    = (int*)alloc((size_t)T * N * SEG * 4);
    int* counts    = (int*)alloc(2048 * 4);
    int* sv        = (int*)alloc((size_t)T * N * CAP * 4);
    float* inorm   = (float*)alloc((size_t)NDIM * 4);
    float* partA   = (float*)alloc((size_t)8 * H1 * B * 4);
    float* AbT     = (float*)alloc((size_t)H1 * B * 4);
    float* W1T     = (float*)alloc((size_t)WVD * H1 * 4);
    float* Wp      = (float*)alloc((size_t)2 * N * H1 * 4);
    float* embs    = (float*)alloc((size_t)N * EMB * 4);
    float* embsT   = (float*)alloc((size_t)EMB * N * 4);
    float* Ahat    = (float*)alloc((size_t)T * N * RC * 4);
    float* wbuf    = (float*)alloc((size_t)T * N * CAP * 64 * 4);
    float* sT      = (float*)alloc((size_t)(STEPS + 1) * NDIM * B * 4);

    k_f1<<<F1_TOT, 256, 0, stream>>>(edge_u, segcnt, inputs, W_in1, partA, W1T,
                                     wordvecs, W_emb, b_emb, embs, embsT);
    k_f2<<<F2_TOT, 256, 0, stream>>>(partA, AbT, wordvecs, W1T, Wp,
                                     embsT, rel_mats, Ahat);
    k_f3<<<F3_TOT, 256, 0, stream>>>(edge_u, edge_v, segcnt,
                                     embs, Ahat, wbuf, inorm, counts, sv,
                                     AbT, Wp, b_in1, W_in2, b_in2, sT);

    for (int s = 0; s < STEPS; s++) {
        int last = (s == STEPS - 1) ? 1 : 0;
        k_step<<<N, 256, 0, stream>>>(counts, sv, wbuf, inorm, sT, s,
                                      W_ih, W_hh, b_ih, b_hh,
                                      W_o1, b_o1, W_o2, b_o2,
                                      sT + (size_t)(s + 1) * NDIM * B, out, last);
    }
}

// Round 21
// 239.337 us; speedup vs baseline: 1.1090x; 1.0614x over previous
//
#include <hip/hip_runtime.h>
#include <math.h>

constexpr int B = 32, N = 1024, ND = 8, FEAT = 2048, WVD = 300;
constexpr int E = 20000, T = 2, STEPS = 5;
constexpr int NDIM = N * ND;            // 8192
constexpr int H1 = 512;
constexpr int W1C = FEAT + WVD;         // 2348
constexpr int EMB = 50;
constexpr int RC = EMB * ND * ND;       // 3200
constexpr int KH = 150;                 // Wv k-split half
constexpr int CAP = 64;                 // fixed row capacity (P(row>64)~1e-20)
constexpr int SEG = 50;                 // fine segments for skip-scan
constexpr int SEGLEN = E / SEG;         // 400 (not mult of 64 — guard)

// k_f1 sections
constexpr int G_KA   = 512;
constexpr int G_W1T  = 16 * 10;
constexpr int G_EMB  = N * 25 / 4;         // 6400
constexpr int G_SEGH = T * N * SEG / 4;    // 25600
constexpr int F1_TOT = G_KA + G_W1T + G_EMB + G_SEGH;

// k_f2 sections
constexpr int G_ARED = 8;
constexpr int G_WV   = 512;
constexpr int G_AHAT = 13 * 32 * T;        // 832
constexpr int F2_TOT = G_ARED + G_WV + G_AHAT;

// k_f3 sections
constexpr int G_INP  = N / 4;              // 256 (4 n per block)
constexpr int F3_TOT = N + G_INP;

// ============ F1: k_A GEMM | W1-transpose | embs(+embsT) | seghist(50) ============
__global__ __launch_bounds__(256) void k_f1(
        const int* eu, int* segcnt,
        const float* inp, const float* W1, float* partA, float* W1T,
        const float* wv, const float* We, const float* be,
        float* embs, float* embsT) {
    __shared__ float smem[8 * 260];
    int tid = threadIdx.x;
    int blk = blockIdx.x;
    if (blk < G_KA) {
        int c = tid & 7, b = tid >> 3;
        int c0 = (blk & 63) * 8;
        int ks = blk >> 6;
        int kt = ks * 256;
        {
            int r = tid >> 5, cb = (tid & 31) * 8;
            const float* src = W1 + (size_t)(c0 + r) * W1C + kt + cb;
            float4 a0 = *(const float4*)src;
            float4 a1 = *(const float4*)(src + 4);
            *(float4*)&smem[r * 260 + cb] = a0;
            *(float4*)&smem[r * 260 + cb + 4] = a1;
        }
        __syncthreads();
        const float* xr = inp + (size_t)b * FEAT + kt;
        float acc = 0.f;
#pragma unroll 8
        for (int k4 = 0; k4 < 64; k4++) {
            float4 x = *(const float4*)(xr + k4 * 4);
            float4 w = *(const float4*)&smem[c * 260 + k4 * 4];
            acc += x.x * w.x + x.y * w.y + x.z * w.z + x.w * w.w;
        }
        partA[(size_t)ks * (H1 * B) + (c0 + c) * B + b] = acc;
    } else if (blk < G_KA + G_W1T) {
        int lb = blk - G_KA;
        int c0 = (lb % 16) * 32, k0 = (lb / 16) * 32;
        float (*tile)[33] = (float(*)[33])smem;
        int kl = tid & 31, cl4 = tid >> 5;
#pragma unroll
        for (int p = 0; p < 4; p++) {
            int c = cl4 + p * 8;
            int k = k0 + kl;
            if (k < WVD) tile[c][kl] = W1[(size_t)(c0 + c) * W1C + FEAT + k];
        }
        __syncthreads();
        int cl = tid & 31, kl4 = tid >> 5;
#pragma unroll
        for (int p = 0; p < 4; p++) {
            int kk = kl4 + p * 8;
            int k = k0 + kk;
            if (k < WVD) W1T[(size_t)k * H1 + c0 + cl] = tile[cl][kk];
        }
    } else if (blk < G_KA + G_W1T + G_EMB) {
        int lb = blk - G_KA - G_W1T;
        int wid = lb * 4 + (tid >> 6);
        int lane = tid & 63;
        int n = wid / 25, cp = wid - n * 25;
        int c0 = cp * 2;
        const float* xr = wv + (size_t)n * WVD;
        const float* wr0 = We + (size_t)c0 * WVD;
        const float* wr1 = wr0 + WVD;
        float a0 = 0.f, a1 = 0.f;
#pragma unroll
        for (int i = 0; i < 5; i++) {
            int k = i * 64 + lane;
            if (k < WVD) {
                float x = xr[k];
                a0 += x * wr0[k];
                a1 += x * wr1[k];
            }
        }
        for (int m = 32; m; m >>= 1) {
            a0 += __shfl_xor(a0, m, 64);
            a1 += __shfl_xor(a1, m, 64);
        }
        if (lane == 0) {
            float v0 = a0 + be[c0], v1 = a1 + be[c0 + 1];
            embs[n * EMB + c0] = v0;
            embs[n * EMB + c0 + 1] = v1;
            embsT[c0 * N + n] = v0;
            embsT[(c0 + 1) * N + n] = v1;
        }
    } else {
        int lb = blk - G_KA - G_W1T - G_EMB;
        int wid = lb * 4 + (tid >> 6);
        int lane = tid & 63;
        int t = wid / (N * SEG);
        int rem = wid - t * (N * SEG);
        int u = rem / SEG, seg = rem - u * SEG;
        const int* eut = eu + t * E;
        int e0 = seg * SEGLEN, e1 = e0 + SEGLEN, cnt = 0;
        for (int c = e0; c < e1; c += 64) {
            int e = c + lane;
            bool ok = (e < e1) && (eut[e] == u);
            cnt += __popcll(__ballot(ok));
        }
        if (lane == 0) segcnt[(t * N + u) * SEG + seg] = cnt;
    }
}

// ============ F2: partA-reduce | Wv GEMM | Ahat GEMM ============
__global__ __launch_bounds__(256) void k_f2(
        const float* partA, float* AbT,
        const float* wv, const float* W1T, float* Wp,
        const float* embsT, const float* RMbase, float* Ahat) {
    __shared__ float smemf[1800];
    int tid = threadIdx.x, blk = blockIdx.x;
    if (blk < G_ARED) {
        int cb = blk * 2048 + tid * 8;
        float4 s0 = {0, 0, 0, 0}, s1 = {0, 0, 0, 0};
#pragma unroll
        for (int ks = 0; ks < 8; ks++) {
            const float* p = partA + (size_t)ks * (H1 * B) + cb;
            float4 a = *(const float4*)p;
            float4 b4 = *(const float4*)(p + 4);
            s0.x += a.x; s0.y += a.y; s0.z += a.z; s0.w += a.w;
            s1.x += b4.x; s1.y += b4.y; s1.z += b4.z; s1.w += b4.w;
        }
        *(float4*)(AbT + cb) = s0;
        *(float4*)(AbT + cb + 4) = s1;
    } else if (blk < G_ARED + G_WV) {
        int lb = blk - G_ARED;
        int kh = lb >> 8;
        int rem = lb & 255;
        int c = (rem & 1) * 256 + tid;
        int n0 = (rem >> 1) * 8;
        int kb = kh * KH;
        float (*el)[8] = (float(*)[8])smemf;
        for (int idx = tid; idx < 8 * KH; idx += 256) {
            int j = idx / KH, k = idx - j * KH;
            el[k][j] = wv[(size_t)(n0 + j) * WVD + kb + k];
        }
        __syncthreads();
        float acc[8] = {};
#pragma unroll 5
        for (int k = 0; k < KH; k++) {
            float r = W1T[(size_t)(kb + k) * H1 + c];
            float4 e0 = *(const float4*)&el[k][0];
            float4 e1 = *(const float4*)&el[k][4];
            acc[0] += e0.x * r; acc[1] += e0.y * r;
            acc[2] += e0.z * r; acc[3] += e0.w * r;
            acc[4] += e1.x * r; acc[5] += e1.y * r;
            acc[6] += e1.z * r; acc[7] += e1.w * r;
        }
        float* wout = Wp + (size_t)kh * N * H1;
#pragma unroll
        for (int j = 0; j < 8; j++) wout[(size_t)(n0 + j) * H1 + c] = acc[j];
    } else {
        int lb = blk - G_ARED - G_WV;
        int t = lb / 416, r = lb % 416;
        int bx = r % 13, by = r / 13;
        const float* RM = RMbase + (size_t)t * EMB * RC;
        float* Ah = Ahat + (size_t)t * N * RC;
        int n0 = by * 32;
        float (*el)[36] = (float(*)[36])smemf;
        for (int idx = tid; idx < EMB * 32; idx += 256)
            el[idx >> 5][idx & 31] = embsT[(idx >> 5) * N + n0 + (idx & 31)];
        __syncthreads();
        int mi = bx * 256 + (tid & 63) * 4;
        int ni = (tid >> 6) * 8;
        if (mi < RC) {
            float acc[8][4] = {};
#pragma unroll 2
            for (int c = 0; c < EMB; c++) {
                float4 rm = *(const float4*)(RM + (size_t)c * RC + mi);
                float4 e0 = *(const float4*)&el[c][ni];
                float4 e1 = *(const float4*)&el[c][ni + 4];
                float ev[8] = {e0.x, e0.y, e0.z, e0.w, e1.x, e1.y, e1.z, e1.w};
#pragma unroll
                for (int j = 0; j < 8; j++) {
                    acc[j][0] += ev[j] * rm.x;
                    acc[j][1] += ev[j] * rm.y;
                    acc[j][2] += ev[j] * rm.z;
                    acc[j][3] += ev[j] * rm.w;
                }
            }
#pragma unroll
            for (int j = 0; j < 8; j++) {
                float4 o = {acc[j][0], acc[j][1], acc[j][2], acc[j][3]};
                *(float4*)(Ah + (size_t)(n0 + ni + j) * RC + mi) = o;
            }
        }
    }
}

// ============ F3: [blk<N] skip-scan row build + weights + norms
//              [blk>=N] inputnet (4 n per block, W2 in LDS) ============
__global__ __launch_bounds__(256) void k_f3(
        const int* eu, const int* ev, const int* segcnt,
        const float* embs, const float* Ahat, float* wbuf, float* inorm,
        int* counts, int* sv,
        const float* AbT, const float* Wp, const float* b1,
        const float* W2, const float* b2, float* sT0) {
    __shared__ float smem[6656];   // 26 KB, carved per branch (R17 layout)
    int tid = threadIdx.x;
    int blk = blockIdx.x;
    if (blk < N) {
        int u = blk;
        float* AL   = smem;                       // [3200]
        int* vl     = (int*)(smem + 3328);        // [T*CAP] = 128
        int* scnt   = vl + T * CAP;               // [T*SEG] = 100
        int* soff   = scnt + T * SEG;             // 100
        int* slist  = soff + T * SEG;             // 100
        int* smeta  = slist + T * SEG;            // nnz[T], ctot[T]
        int w = tid >> 6, lane = tid & 63;
        if (tid < T * SEG) {
            int t = tid / SEG, s = tid - t * SEG;
            scnt[tid] = segcnt[((size_t)t * N + u) * SEG + s];
        }
        __syncthreads();
        if (w < T && lane == 0) {
            int off = 0, nn = 0;
            for (int j = 0; j < SEG; j++) {
                int c = scnt[w * SEG + j];
                soff[w * SEG + j] = off;
                off += c;
                if (c > 0) slist[w * SEG + nn++] = j;
            }
            smeta[w] = nn;          // nnz
            smeta[T + w] = off;     // total count
            counts[w * N + u] = off;
        }
        __syncthreads();
        // scatter: 2 waves per row, round-robin over nonzero segments
        {
            int myrow = w >> 1, sub = w & 1;
            int row = myrow * N + u;
            const int* eut = eu + myrow * E;
            const int* evt = ev + myrow * E;
            int nnz = smeta[myrow];
            for (int idx = sub; idx < nnz; idx += 2) {
                int seg = slist[myrow * SEG + idx];
                int base = soff[myrow * SEG + seg];
                int e0 = seg * SEGLEN, e1 = e0 + SEGLEN, cnt = 0;
                for (int c = e0; c < e1; c += 64) {
                    int e = c + lane;
                    bool ok = (e < e1) && (eut[e] == u);
                    unsigned long long m = __ballot(ok);
                    if (ok) {
                        int rank = __popcll(m & ((1ull << lane) - 1));
                        int pos = base + cnt + rank;
                        vl[myrow * CAP + pos] = evt[e];
                        sv[(size_t)row * CAP + pos] = evt[e];
                    }
                    cnt += __popcll(m);
                }
            }
        }
        __syncthreads();
        int cnts[T];
#pragma unroll
        for (int t = 0; t < T; t++) cnts[t] = smeta[T + t];
        // edge weights + fused norms (float4-staged panel — sole change vs R17)
        int k = lane;
        float ssq = 0.f;
        for (int t = 0; t < T; t++) {
            __syncthreads();
            {
                const float4* asrc = (const float4*)(Ahat + ((size_t)t * N + u) * RC);
                float4* adst = (float4*)AL;
                for (int idx = tid; idx < RC / 4; idx += 256)
                    adst[idx] = asrc[idx];
            }
            __syncthreads();
            int cnt = cnts[t];
            size_t base = (size_t)(t * N + u) * CAP;
            for (int i = w; i < cnt; i += 4) {
                int v = vl[t * CAP + i];
                const float* vr = embs + v * EMB;
                float acc = 0.f;
#pragma unroll 10
                for (int d = 0; d < EMB; d++) acc += vr[d] * AL[d * 64 + k];
                wbuf[(base + i) * 64 + k] = acc;
                ssq += acc * acc;
            }
        }
        __syncthreads();
        AL[w * 64 + k] = ssq;
        __syncthreads();
        if (tid < 64) {
            float tot = AL[tid] + AL[64 + tid] + AL[128 + tid] + AL[192 + tid];
            tot += __shfl_xor(tot, 1, 64);
            tot += __shfl_xor(tot, 2, 64);
            tot += __shfl_xor(tot, 4, 64);
            int ki = tid >> 3, kj = tid & 7;
            if (kj == 0) {
                float nv = sqrtf(tot);
                if (nv == 0.f) nv = 1.f;
                inorm[u * ND + ki] = 1.0f / nv;
            }
        }
    } else {
        // inputnet: 4 n per block, W2 staged in LDS (R17 layout)
        int n0 = (blk - N) * 4;
        float* w2s  = smem;            // 4096
        float* wvs  = smem + 4096;     // 512
        float* part = smem + 4608;     // 2048
        for (int idx = tid; idx < 8 * H1; idx += 256) w2s[idx] = W2[idx];
        int b = tid & 31, s = tid >> 5;
        int ki2 = tid >> 5, b2i = tid & 31;
        for (int nn = 0; nn < 4; nn++) {
            int n = n0 + nn;
            __syncthreads();
            for (int idx = tid; idx < H1; idx += 256)
                wvs[idx] = Wp[(size_t)n * H1 + idx]
                         + Wp[(size_t)N * H1 + (size_t)n * H1 + idx] + b1[idx];
            __syncthreads();
            float acc[8] = {};
            for (int i = 0; i < 64; i++) {
                int c = s * 64 + i;
                float tv = fmaxf(AbT[c * 32 + b] + wvs[c], 0.f);
#pragma unroll
                for (int ki = 0; ki < 8; ki++) acc[ki] += tv * w2s[ki * H1 + c];
            }
#pragma unroll
            for (int ki = 0; ki < 8; ki++) part[s * 256 + ki * 32 + b] = acc[ki];
            __syncthreads();
            float tot = b2[ki2];
#pragma unroll
            for (int s2 = 0; s2 < 8; s2++) tot += part[s2 * 256 + ki2 * 32 + b2i];
            sT0[(size_t)n * 256 + tid] = tot;
        }
    }
}

// ============ propagation step: 2-edge-unrolled SpMM (inline inorm) + GRU ============
__global__ __launch_bounds__(256) void k_step(
        const int* counts, const int* sv,
        const float* wbuf, const float* inorm, const float* sT, int s,
        const float* W_ih, const float* W_hh, const float* b_ih, const float* b_hh,
        const float* Wo1, const float* bo1, const float* Wo2, const float* bo2,
        float* sOut, float* out, int last) {
    __shared__ float xs[256], hs[256], hfin[256];
    __shared__ float wih[192], whh[192];
    __shared__ float w1s[160], b1s[20], w2s[20];
    __shared__ float res[8][33];
    int tid = threadIdx.x;
    int u = blockIdx.x;
    int ki = tid >> 5, b = tid & 31;
    if (tid < 192) { wih[tid] = W_ih[tid]; whh[tid] = W_hh[tid]; }
    if (last) {
        if (tid < 160) w1s[tid] = Wo1[tid];
        if (tid < 20) { b1s[tid] = bo1[tid]; w2s[tid] = Wo2[tid]; }
    }
    const float* sIn = sT + (size_t)s * NDIM * B;
    float hown = sIn[((size_t)u * 8 + ki) * B + b];
    float acc = 0.f;
    for (int t = 0; t < T; t++) {
        int row = t * N + u;
        int cnt = counts[row];
        size_t base = (size_t)row * CAP;
        int i = 0;
        for (; i + 1 < cnt; i += 2) {
            size_t s0 = base + i, s1 = base + i + 1;
            int v0 = sv[s0], v1 = sv[s1];
            const float* wp0 = wbuf + s0 * 64 + ki * 8;
            const float* wp1 = wbuf + s1 * 64 + ki * 8;
            float4 wa0 = *(const float4*)wp0;
            float4 wb0 = *(const float4*)(wp0 + 4);
            float4 wa1 = *(const float4*)wp1;
            float4 wb1 = *(const float4*)(wp1 + 4);
            const float* ip0 = inorm + v0 * ND;
            const float* ip1 = inorm + v1 * ND;
            const float* hp0 = sIn + (size_t)v0 * 256 + b;
            const float* hp1 = sIn + (size_t)v1 * 256 + b;
            acc += (wa0.x * ip0[0]) * hp0[0]   + (wa0.y * ip0[1]) * hp0[32]
                 + (wa0.z * ip0[2]) * hp0[64]  + (wa0.w * ip0[3]) * hp0[96]
                 + (wb0.x * ip0[4]) * hp0[128] + (wb0.y * ip0[5]) * hp0[160]
                 + (wb0.z * ip0[6]) * hp0[192] + (wb0.w * ip0[7]) * hp0[224];
            acc += (wa1.x * ip1[0]) * hp1[0]   + (wa1.y * ip1[1]) * hp1[32]
                 + (wa1.z * ip1[2]) * hp1[64]  + (wa1.w * ip1[3]) * hp1[96]
                 + (wb1.x * ip1[4]) * hp1[128] + (wb1.y * ip1[5]) * hp1[160]
                 + (wb1.z * ip1[6]) * hp1[192] + (wb1.w * ip1[7]) * hp1[224];
        }
        if (i < cnt) {
            size_t s0 = base + i;
            int v0 = sv[s0];
            const float* wp0 = wbuf + s0 * 64 + ki * 8;
            float4 wa0 = *(const float4*)wp0;
            float4 wb0 = *(const float4*)(wp0 + 4);
            const float* ip0 = inorm + v0 * ND;
            const float* hp0 = sIn + (size_t)v0 * 256 + b;
            acc += (wa0.x * ip0[0]) * hp0[0]   + (wa0.y * ip0[1]) * hp0[32]
                 + (wa0.z * ip0[2]) * hp0[64]  + (wa0.w * ip0[3]) * hp0[96]
                 + (wb0.x * ip0[4]) * hp0[128] + (wb0.y * ip0[5]) * hp0[160]
                 + (wb0.z * ip0[6]) * hp0[192] + (wb0.w * ip0[7]) * hp0[224];
        }
    }
    float xv = tanhf(acc);
    xs[ki * 32 + b] = xv;
    hs[ki * 32 + b] = hown;
    __syncthreads();
    float gr = b_ih[ki], gz = b_ih[8 + ki], gn = b_ih[16 + ki];
    float hr = b_hh[ki], hz = b_hh[8 + ki], hn = b_hh[16 + ki];
#pragma unroll
    for (int j = 0; j < 8; j++) {
        float xj = xs[j * 32 + b], hj = hs[j * 32 + b];
        gr += wih[ki * 8 + j] * xj;
        gz += wih[(8 + ki) * 8 + j] * xj;
        gn += wih[(16 + ki) * 8 + j] * xj;
        hr += whh[ki * 8 + j] * hj;
        hz += whh[(8 + ki) * 8 + j] * hj;
        hn += whh[(16 + ki) * 8 + j] * hj;
    }
    float r = 1.f / (1.f + expf(-(gr + hr)));
    float z = 1.f / (1.f + expf(-(gz + hz)));
    float nn = tanhf(gn + r * hn);
    float hnew = (1.f - z) * nn + z * hown;
    if (!last) {
        sOut[((size_t)u * 8 + ki) * B + b] = hnew;
        return;
    }
    hfin[ki * 32 + b] = hnew;
    __syncthreads();
    int s6 = tid >> 5, bb = tid & 31;
    if (s6 < 6) {
        float x[8];
#pragma unroll
        for (int kk = 0; kk < 8; kk++)
            x[kk] = (s6 < STEPS)
                ? sT[((size_t)s6 * NDIM + u * 8 + kk) * B + bb]
                : hfin[kk * 32 + bb];
        float accv = bo2[0];
#pragma unroll
        for (int j = 0; j < 20; j++) {
            float h = b1s[j];
#pragma unroll
            for (int kk = 0; kk < 8; kk++) h += w1s[j * 8 + kk] * x[kk];
            h = fmaxf(h, 0.f);
            accv += w2s[j] * h;
        }
        res[s6][bb] = accv;
    }
    __syncthreads();
    if (tid < 192) {
        int b_w = tid / 6, s_w = tid - b_w * 6;
        out[(size_t)b_w * ((STEPS + 1) * N) + u * (STEPS + 1) + s_w] = res[s_w][b_w];
    }
}

extern "C" void kernel_launch(void* const* d_in, const int* in_sizes, int n_in,
                              void* d_out, int out_size, void* d_ws, size_t ws_size,
                              hipStream_t stream) {
    const float* inputs   = (const float*)d_in[0];
    const float* wordvecs = (const float*)d_in[1];
    const int*   edge_u   = (const int*)d_in[2];
    const int*   edge_v   = (const int*)d_in[3];
    const float* W_in1 = (const float*)d_in[6];
    const float* b_in1 = (const float*)d_in[7];
    const float* W_in2 = (const float*)d_in[8];
    const float* b_in2 = (const float*)d_in[9];
    const float* W_emb = (const float*)d_in[10];
    const float* b_emb = (const float*)d_in[11];
    const float* rel_mats = (const float*)d_in[12];
    const float* W_ih = (const float*)d_in[13];
    const float* W_hh = (const float*)d_in[14];
    const float* b_ih = (const float*)d_in[15];
    const float* b_hh = (const float*)d_in[16];
    const float* W_o1 = (const float*)d_in[17];
    const float* b_o1 = (const float*)d_in[18];
    const float* W_o2 = (const float*)d_in[19];
    const float* b_o2 = (const float*)d_in[20];
    float* out = (float*)d_out;

    char* ws = (char*)d_ws;
    size_t off = 0;
    auto alloc = [&](size_t bytes) -> void* {
        void* p = ws + off;
        off = (off + bytes + 255) & ~(size_t)255;
        return p;
    };
    int* segcnt    = (int*)alloc((size_t)T * N * SEG * 4);
    int* counts    = (int*)alloc(2048 * 4);
    int* sv        = (int*)alloc((size_t)T * N * CAP * 4);
    float* inorm   = (float*)alloc((size_t)NDIM * 4);
    float* partA   = (float*)alloc((size_t)8 * H1 * B * 4);
    float* AbT     = (float*)alloc((size_t)H1 * B * 4);
    float* W1T     = (float*)alloc((size_t)WVD * H1 * 4);
    float* Wp      = (float*)alloc((size_t)2 * N * H1 * 4);
    float* embs    = (float*)alloc((size_t)N * EMB * 4);
    float* embsT   = (float*)alloc((size_t)EMB * N * 4);
    float* Ahat    = (float*)alloc((size_t)T * N * RC * 4);
    float* wbuf    = (float*)alloc((size_t)T * N * CAP * 64 * 4);
    float* sT      = (float*)alloc((size_t)(STEPS + 1) * NDIM * B * 4);

    k_f1<<<F1_TOT, 256, 0, stream>>>(edge_u, segcnt, inputs, W_in1, partA, W1T,
                                     wordvecs, W_emb, b_emb, embs, embsT);
    k_f2<<<F2_TOT, 256, 0, stream>>>(partA, AbT, wordvecs, W1T, Wp,
                                     embsT, rel_mats, Ahat);
    k_f3<<<F3_TOT, 256, 0, stream>>>(edge_u, edge_v, segcnt,
                                     embs, Ahat, wbuf, inorm, counts, sv,
                                     AbT, Wp, b_in1, W_in2, b_in2, sT);

    for (int s = 0; s < STEPS; s++) {
        int last = (s == STEPS - 1) ? 1 : 0;
        k_step<<<N, 256, 0, stream>>>(counts, sv, wbuf, inorm, sT, s,
                                      W_ih, W_hh, b_ih, b_hh,
                                      W_o1, b_o1, W_o2, b_o2,
                                      sT + (size_t)(s + 1) * NDIM * B, out, last);
    }
}

// Round 22
// 239.239 us; speedup vs baseline: 1.1095x; 1.0004x over previous
//
#include <hip/hip_runtime.h>
#include <math.h>

constexpr int B = 32, N = 1024, ND = 8, FEAT = 2048, WVD = 300;
constexpr int E = 20000, T = 2, STEPS = 5;
constexpr int NDIM = N * ND;            // 8192
constexpr int H1 = 512;
constexpr int W1C = FEAT + WVD;         // 2348
constexpr int EMB = 50;
constexpr int RC = EMB * ND * ND;       // 3200
constexpr int KH = 150;                 // Wv k-split half
constexpr int CAP = 64;                 // fixed row capacity (P(row>64)~1e-20)
constexpr int SEG = 50;                 // fine segments for skip-scan
constexpr int SEGLEN = E / SEG;         // 400 (not mult of 64 — guard)

// k_f1 sections
constexpr int G_KA   = 512;
constexpr int G_W1T  = 16 * 10;
constexpr int G_EMB  = N * 25 / 4;         // 6400
constexpr int G_SEGH = T * N * SEG / 4;    // 25600
constexpr int F1_TOT = G_KA + G_W1T + G_EMB + G_SEGH;

// k_f2 sections
constexpr int G_ARED = 8;
constexpr int G_WV   = 512;
constexpr int G_AHAT = 13 * 32 * T;        // 832
constexpr int F2_TOT = G_ARED + G_WV + G_AHAT;

// k_f3 sections
constexpr int G_INP  = N / 4;              // 256 (4 n per block)
constexpr int F3_TOT = N + G_INP;

// ============ F1: k_A GEMM | W1-transpose | embs(+embsT) | seghist(50) ============
__global__ __launch_bounds__(256) void k_f1(
        const int* eu, int* segcnt,
        const float* inp, const float* W1, float* partA, float* W1T,
        const float* wv, const float* We, const float* be,
        float* embs, float* embsT) {
    __shared__ float smem[8 * 260];
    int tid = threadIdx.x;
    int blk = blockIdx.x;
    if (blk < G_KA) {
        int c = tid & 7, b = tid >> 3;
        int c0 = (blk & 63) * 8;
        int ks = blk >> 6;
        int kt = ks * 256;
        {
            int r = tid >> 5, cb = (tid & 31) * 8;
            const float* src = W1 + (size_t)(c0 + r) * W1C + kt + cb;
            float4 a0 = *(const float4*)src;
            float4 a1 = *(const float4*)(src + 4);
            *(float4*)&smem[r * 260 + cb] = a0;
            *(float4*)&smem[r * 260 + cb + 4] = a1;
        }
        __syncthreads();
        const float* xr = inp + (size_t)b * FEAT + kt;
        float acc = 0.f;
#pragma unroll 8
        for (int k4 = 0; k4 < 64; k4++) {
            float4 x = *(const float4*)(xr + k4 * 4);
            float4 w = *(const float4*)&smem[c * 260 + k4 * 4];
            acc += x.x * w.x + x.y * w.y + x.z * w.z + x.w * w.w;
        }
        partA[(size_t)ks * (H1 * B) + (c0 + c) * B + b] = acc;
    } else if (blk < G_KA + G_W1T) {
        int lb = blk - G_KA;
        int c0 = (lb % 16) * 32, k0 = (lb / 16) * 32;
        float (*tile)[33] = (float(*)[33])smem;
        int kl = tid & 31, cl4 = tid >> 5;
#pragma unroll
        for (int p = 0; p < 4; p++) {
            int c = cl4 + p * 8;
            int k = k0 + kl;
            if (k < WVD) tile[c][kl] = W1[(size_t)(c0 + c) * W1C + FEAT + k];
        }
        __syncthreads();
        int cl = tid & 31, kl4 = tid >> 5;
#pragma unroll
        for (int p = 0; p < 4; p++) {
            int kk = kl4 + p * 8;
            int k = k0 + kk;
            if (k < WVD) W1T[(size_t)k * H1 + c0 + cl] = tile[cl][kk];
        }
    } else if (blk < G_KA + G_W1T + G_EMB) {
        int lb = blk - G_KA - G_W1T;
        int wid = lb * 4 + (tid >> 6);
        int lane = tid & 63;
        int n = wid / 25, cp = wid - n * 25;
        int c0 = cp * 2;
        const float* xr = wv + (size_t)n * WVD;
        const float* wr0 = We + (size_t)c0 * WVD;
        const float* wr1 = wr0 + WVD;
        float a0 = 0.f, a1 = 0.f;
#pragma unroll
        for (int i = 0; i < 5; i++) {
            int k = i * 64 + lane;
            if (k < WVD) {
                float x = xr[k];
                a0 += x * wr0[k];
                a1 += x * wr1[k];
            }
        }
        for (int m = 32; m; m >>= 1) {
            a0 += __shfl_xor(a0, m, 64);
            a1 += __shfl_xor(a1, m, 64);
        }
        if (lane == 0) {
            float v0 = a0 + be[c0], v1 = a1 + be[c0 + 1];
            embs[n * EMB + c0] = v0;
            embs[n * EMB + c0 + 1] = v1;
            embsT[c0 * N + n] = v0;
            embsT[(c0 + 1) * N + n] = v1;
        }
    } else {
        int lb = blk - G_KA - G_W1T - G_EMB;
        int wid = lb * 4 + (tid >> 6);
        int lane = tid & 63;
        int t = wid / (N * SEG);
        int rem = wid - t * (N * SEG);
        int u = rem / SEG, seg = rem - u * SEG;
        const int* eut = eu + t * E;
        int e0 = seg * SEGLEN, e1 = e0 + SEGLEN, cnt = 0;
        for (int c = e0; c < e1; c += 64) {
            int e = c + lane;
            bool ok = (e < e1) && (eut[e] == u);
            cnt += __popcll(__ballot(ok));
        }
        if (lane == 0) segcnt[(t * N + u) * SEG + seg] = cnt;
    }
}

// ============ F2: partA-reduce | Wv GEMM | Ahat GEMM ============
__global__ __launch_bounds__(256) void k_f2(
        const float* partA, float* AbT,
        const float* wv, const float* W1T, float* Wp,
        const float* embsT, const float* RMbase, float* Ahat) {
    __shared__ float smemf[1800];
    int tid = threadIdx.x, blk = blockIdx.x;
    if (blk < G_ARED) {
        int cb = blk * 2048 + tid * 8;
        float4 s0 = {0, 0, 0, 0}, s1 = {0, 0, 0, 0};
#pragma unroll
        for (int ks = 0; ks < 8; ks++) {
            const float* p = partA + (size_t)ks * (H1 * B) + cb;
            float4 a = *(const float4*)p;
            float4 b4 = *(const float4*)(p + 4);
            s0.x += a.x; s0.y += a.y; s0.z += a.z; s0.w += a.w;
            s1.x += b4.x; s1.y += b4.y; s1.z += b4.z; s1.w += b4.w;
        }
        *(float4*)(AbT + cb) = s0;
        *(float4*)(AbT + cb + 4) = s1;
    } else if (blk < G_ARED + G_WV) {
        int lb = blk - G_ARED;
        int kh = lb >> 8;
        int rem = lb & 255;
        int c = (rem & 1) * 256 + tid;
        int n0 = (rem >> 1) * 8;
        int kb = kh * KH;
        float (*el)[8] = (float(*)[8])smemf;
        for (int idx = tid; idx < 8 * KH; idx += 256) {
            int j = idx / KH, k = idx - j * KH;
            el[k][j] = wv[(size_t)(n0 + j) * WVD + kb + k];
        }
        __syncthreads();
        float acc[8] = {};
#pragma unroll 5
        for (int k = 0; k < KH; k++) {
            float r = W1T[(size_t)(kb + k) * H1 + c];
            float4 e0 = *(const float4*)&el[k][0];
            float4 e1 = *(const float4*)&el[k][4];
            acc[0] += e0.x * r; acc[1] += e0.y * r;
            acc[2] += e0.z * r; acc[3] += e0.w * r;
            acc[4] += e1.x * r; acc[5] += e1.y * r;
            acc[6] += e1.z * r; acc[7] += e1.w * r;
        }
        float* wout = Wp + (size_t)kh * N * H1;
#pragma unroll
        for (int j = 0; j < 8; j++) wout[(size_t)(n0 + j) * H1 + c] = acc[j];
    } else {
        int lb = blk - G_ARED - G_WV;
        int t = lb / 416, r = lb % 416;
        int bx = r % 13, by = r / 13;
        const float* RM = RMbase + (size_t)t * EMB * RC;
        float* Ah = Ahat + (size_t)t * N * RC;
        int n0 = by * 32;
        float (*el)[36] = (float(*)[36])smemf;
        for (int idx = tid; idx < EMB * 32; idx += 256)
            el[idx >> 5][idx & 31] = embsT[(idx >> 5) * N + n0 + (idx & 31)];
        __syncthreads();
        int mi = bx * 256 + (tid & 63) * 4;
        int ni = (tid >> 6) * 8;
        if (mi < RC) {
            float acc[8][4] = {};
#pragma unroll 2
            for (int c = 0; c < EMB; c++) {
                float4 rm = *(const float4*)(RM + (size_t)c * RC + mi);
                float4 e0 = *(const float4*)&el[c][ni];
                float4 e1 = *(const float4*)&el[c][ni + 4];
                float ev[8] = {e0.x, e0.y, e0.z, e0.w, e1.x, e1.y, e1.z, e1.w};
#pragma unroll
                for (int j = 0; j < 8; j++) {
                    acc[j][0] += ev[j] * rm.x;
                    acc[j][1] += ev[j] * rm.y;
                    acc[j][2] += ev[j] * rm.z;
                    acc[j][3] += ev[j] * rm.w;
                }
            }
#pragma unroll
            for (int j = 0; j < 8; j++) {
                float4 o = {acc[j][0], acc[j][1], acc[j][2], acc[j][3]};
                *(float4*)(Ah + (size_t)(n0 + ni + j) * RC + mi) = o;
            }
        }
    }
}

// ============ F3: [blk<N] skip-scan build + single-phase dual-panel staging
//              [blk>=N] inputnet (4 n per block, W2 in LDS) ============
__global__ __launch_bounds__(256) void k_f3(
        const int* eu, const int* ev, const int* segcnt,
        const float* embs, const float* Ahat, float* wbuf, float* inorm,
        int* counts, int* sv,
        const float* AbT, const float* Wp, const float* b1,
        const float* W2, const float* b2, float* sT0) {
    __shared__ float smem[6832];   // 27.3 KB max over branches
    int tid = threadIdx.x;
    int blk = blockIdx.x;
    if (blk < N) {
        int u = blk;
        float* AL   = smem;                       // [2*RC] = 6400
        int* vl     = (int*)(smem + 2 * RC);      // [T*CAP] = 128
        int* scnt   = vl + T * CAP;               // [T*SEG] = 100
        int* soff   = scnt + T * SEG;             // 100
        int* slist  = soff + T * SEG;             // 100
        int* smeta  = slist + T * SEG;            // nnz[T], ctot[T]
        int w = tid >> 6, lane = tid & 63;
        if (tid < T * SEG) {
            int t = tid / SEG, s = tid - t * SEG;
            scnt[tid] = segcnt[((size_t)t * N + u) * SEG + s];
        }
        __syncthreads();
        if (w < T && lane == 0) {
            int off = 0, nn = 0;
            for (int j = 0; j < SEG; j++) {
                int c = scnt[w * SEG + j];
                soff[w * SEG + j] = off;
                off += c;
                if (c > 0) slist[w * SEG + nn++] = j;
            }
            smeta[w] = nn;          // nnz
            smeta[T + w] = off;     // total count
            counts[w * N + u] = off;
        }
        __syncthreads();
        // scatter: 2 waves per row, round-robin over nonzero segments
        {
            int myrow = w >> 1, sub = w & 1;
            int row = myrow * N + u;
            const int* eut = eu + myrow * E;
            const int* evt = ev + myrow * E;
            int nnz = smeta[myrow];
            for (int idx = sub; idx < nnz; idx += 2) {
                int seg = slist[myrow * SEG + idx];
                int base = soff[myrow * SEG + seg];
                int e0 = seg * SEGLEN, e1 = e0 + SEGLEN, cnt = 0;
                for (int c = e0; c < e1; c += 64) {
                    int e = c + lane;
                    bool ok = (e < e1) && (eut[e] == u);
                    unsigned long long m = __ballot(ok);
                    if (ok) {
                        int rank = __popcll(m & ((1ull << lane) - 1));
                        int pos = base + cnt + rank;
                        vl[myrow * CAP + pos] = evt[e];
                        sv[(size_t)row * CAP + pos] = evt[e];
                    }
                    cnt += __popcll(m);
                }
            }
        }
        // single-phase staging: BOTH Ahat panels, 2x outstanding loads
        {
            const float4* a0 = (const float4*)(Ahat + (size_t)u * RC);
            const float4* a1 = (const float4*)(Ahat + ((size_t)N + u) * RC);
            float4* d0 = (float4*)AL;
            float4* d1 = (float4*)(AL + RC);
            for (int idx = tid; idx < RC / 4; idx += 256) {
                d0[idx] = a0[idx];
                d1[idx] = a1[idx];
            }
        }
        __syncthreads();
        int cnts[T];
#pragma unroll
        for (int t = 0; t < T; t++) cnts[t] = smeta[T + t];
        // edge weights + fused norms
        int k = lane;
        float ssq = 0.f;
        for (int t = 0; t < T; t++) {
            const float* ALt = AL + t * RC;
            int cnt = cnts[t];
            size_t base = (size_t)(t * N + u) * CAP;
            for (int i = w; i < cnt; i += 4) {
                int v = vl[t * CAP + i];
                const float* vr = embs + v * EMB;
                float acc = 0.f;
#pragma unroll 10
                for (int d = 0; d < EMB; d++) acc += vr[d] * ALt[d * 64 + k];
                wbuf[(base + i) * 64 + k] = acc;
                ssq += acc * acc;
            }
        }
        __syncthreads();
        AL[w * 64 + k] = ssq;
        __syncthreads();
        if (tid < 64) {
            float tot = AL[tid] + AL[64 + tid] + AL[128 + tid] + AL[192 + tid];
            tot += __shfl_xor(tot, 1, 64);
            tot += __shfl_xor(tot, 2, 64);
            tot += __shfl_xor(tot, 4, 64);
            int ki = tid >> 3, kj = tid & 7;
            if (kj == 0) {
                float nv = sqrtf(tot);
                if (nv == 0.f) nv = 1.f;
                inorm[u * ND + ki] = 1.0f / nv;
            }
        }
    } else {
        // inputnet: 4 n per block, W2 staged in LDS (R17 layout)
        int n0 = (blk - N) * 4;
        float* w2s  = smem;            // 4096
        float* wvs  = smem + 4096;     // 512
        float* part = smem + 4608;     // 2048
        for (int idx = tid; idx < 8 * H1; idx += 256) w2s[idx] = W2[idx];
        int b = tid & 31, s = tid >> 5;
        int ki2 = tid >> 5, b2i = tid & 31;
        for (int nn = 0; nn < 4; nn++) {
            int n = n0 + nn;
            __syncthreads();
            for (int idx = tid; idx < H1; idx += 256)
                wvs[idx] = Wp[(size_t)n * H1 + idx]
                         + Wp[(size_t)N * H1 + (size_t)n * H1 + idx] + b1[idx];
            __syncthreads();
            float acc[8] = {};
            for (int i = 0; i < 64; i++) {
                int c = s * 64 + i;
                float tv = fmaxf(AbT[c * 32 + b] + wvs[c], 0.f);
#pragma unroll
                for (int ki = 0; ki < 8; ki++) acc[ki] += tv * w2s[ki * H1 + c];
            }
#pragma unroll
            for (int ki = 0; ki < 8; ki++) part[s * 256 + ki * 32 + b] = acc[ki];
            __syncthreads();
            float tot = b2[ki2];
#pragma unroll
            for (int s2 = 0; s2 < 8; s2++) tot += part[s2 * 256 + ki2 * 32 + b2i];
            sT0[(size_t)n * 256 + tid] = tot;
        }
    }
}

// ============ propagation step: 2-edge-unrolled SpMM (inline inorm) + GRU ============
__global__ __launch_bounds__(256) void k_step(
        const int* counts, const int* sv,
        const float* wbuf, const float* inorm, const float* sT, int s,
        const float* W_ih, const float* W_hh, const float* b_ih, const float* b_hh,
        const float* Wo1, const float* bo1, const float* Wo2, const float* bo2,
        float* sOut, float* out, int last) {
    __shared__ float xs[256], hs[256], hfin[256];
    __shared__ float wih[192], whh[192];
    __shared__ float w1s[160], b1s[20], w2s[20];
    __shared__ float res[8][33];
    int tid = threadIdx.x;
    int u = blockIdx.x;
    int ki = tid >> 5, b = tid & 31;
    if (tid < 192) { wih[tid] = W_ih[tid]; whh[tid] = W_hh[tid]; }
    if (last) {
        if (tid < 160) w1s[tid] = Wo1[tid];
        if (tid < 20) { b1s[tid] = bo1[tid]; w2s[tid] = Wo2[tid]; }
    }
    const float* sIn = sT + (size_t)s * NDIM * B;
    float hown = sIn[((size_t)u * 8 + ki) * B + b];
    float acc = 0.f;
    for (int t = 0; t < T; t++) {
        int row = t * N + u;
        int cnt = counts[row];
        size_t base = (size_t)row * CAP;
        int i = 0;
        for (; i + 1 < cnt; i += 2) {
            size_t s0 = base + i, s1 = base + i + 1;
            int v0 = sv[s0], v1 = sv[s1];
            const float* wp0 = wbuf + s0 * 64 + ki * 8;
            const float* wp1 = wbuf + s1 * 64 + ki * 8;
            float4 wa0 = *(const float4*)wp0;
            float4 wb0 = *(const float4*)(wp0 + 4);
            float4 wa1 = *(const float4*)wp1;
            float4 wb1 = *(const float4*)(wp1 + 4);
            const float* ip0 = inorm + v0 * ND;
            const float* ip1 = inorm + v1 * ND;
            const float* hp0 = sIn + (size_t)v0 * 256 + b;
            const float* hp1 = sIn + (size_t)v1 * 256 + b;
            acc += (wa0.x * ip0[0]) * hp0[0]   + (wa0.y * ip0[1]) * hp0[32]
                 + (wa0.z * ip0[2]) * hp0[64]  + (wa0.w * ip0[3]) * hp0[96]
                 + (wb0.x * ip0[4]) * hp0[128] + (wb0.y * ip0[5]) * hp0[160]
                 + (wb0.z * ip0[6]) * hp0[192] + (wb0.w * ip0[7]) * hp0[224];
            acc += (wa1.x * ip1[0]) * hp1[0]   + (wa1.y * ip1[1]) * hp1[32]
                 + (wa1.z * ip1[2]) * hp1[64]  + (wa1.w * ip1[3]) * hp1[96]
                 + (wb1.x * ip1[4]) * hp1[128] + (wb1.y * ip1[5]) * hp1[160]
                 + (wb1.z * ip1[6]) * hp1[192] + (wb1.w * ip1[7]) * hp1[224];
        }
        if (i < cnt) {
            size_t s0 = base + i;
            int v0 = sv[s0];
            const float* wp0 = wbuf + s0 * 64 + ki * 8;
            float4 wa0 = *(const float4*)wp0;
            float4 wb0 = *(const float4*)(wp0 + 4);
            const float* ip0 = inorm + v0 * ND;
            const float* hp0 = sIn + (size_t)v0 * 256 + b;
            acc += (wa0.x * ip0[0]) * hp0[0]   + (wa0.y * ip0[1]) * hp0[32]
                 + (wa0.z * ip0[2]) * hp0[64]  + (wa0.w * ip0[3]) * hp0[96]
                 + (wb0.x * ip0[4]) * hp0[128] + (wb0.y * ip0[5]) * hp0[160]
                 + (wb0.z * ip0[6]) * hp0[192] + (wb0.w * ip0[7]) * hp0[224];
        }
    }
    float xv = tanhf(acc);
    xs[ki * 32 + b] = xv;
    hs[ki * 32 + b] = hown;
    __syncthreads();
    float gr = b_ih[ki], gz = b_ih[8 + ki], gn = b_ih[16 + ki];
    float hr = b_hh[ki], hz = b_hh[8 + ki], hn = b_hh[16 + ki];
#pragma unroll
    for (int j = 0; j < 8; j++) {
        float xj = xs[j * 32 + b], hj = hs[j * 32 + b];
        gr += wih[ki * 8 + j] * xj;
        gz += wih[(8 + ki) * 8 + j] * xj;
        gn += wih[(16 + ki) * 8 + j] * xj;
        hr += whh[ki * 8 + j] * hj;
        hz += whh[(8 + ki) * 8 + j] * hj;
        hn += whh[(16 + ki) * 8 + j] * hj;
    }
    float r = 1.f / (1.f + expf(-(gr + hr)));
    float z = 1.f / (1.f + expf(-(gz + hz)));
    float nn = tanhf(gn + r * hn);
    float hnew = (1.f - z) * nn + z * hown;
    if (!last) {
        sOut[((size_t)u * 8 + ki) * B + b] = hnew;
        return;
    }
    hfin[ki * 32 + b] = hnew;
    __syncthreads();
    int s6 = tid >> 5, bb = tid & 31;
    if (s6 < 6) {
        float x[8];
#pragma unroll
        for (int kk = 0; kk < 8; kk++)
            x[kk] = (s6 < STEPS)
                ? sT[((size_t)s6 * NDIM + u * 8 + kk) * B + bb]
                : hfin[kk * 32 + bb];
        float accv = bo2[0];
#pragma unroll
        for (int j = 0; j < 20; j++) {
            float h = b1s[j];
#pragma unroll
            for (int kk = 0; kk < 8; kk++) h += w1s[j * 8 + kk] * x[kk];
            h = fmaxf(h, 0.f);
            accv += w2s[j] * h;
        }
        res[s6][bb] = accv;
    }
    __syncthreads();
    if (tid < 192) {
        int b_w = tid / 6, s_w = tid - b_w * 6;
        out[(size_t)b_w * ((STEPS + 1) * N) + u * (STEPS + 1) + s_w] = res[s_w][b_w];
    }
}

extern "C" void kernel_launch(void* const* d_in, const int* in_sizes, int n_in,
                              void* d_out, int out_size, void* d_ws, size_t ws_size,
                              hipStream_t stream) {
    const float* inputs   = (const float*)d_in[0];
    const float* wordvecs = (const float*)d_in[1];
    const int*   edge_u   = (const int*)d_in[2];
    const int*   edge_v   = (const int*)d_in[3];
    const float* W_in1 = (const float*)d_in[6];
    const float* b_in1 = (const float*)d_in[7];
    const float* W_in2 = (const float*)d_in[8];
    const float* b_in2 = (const float*)d_in[9];
    const float* W_emb = (const float*)d_in[10];
    const float* b_emb = (const float*)d_in[11];
    const float* rel_mats = (const float*)d_in[12];
    const float* W_ih = (const float*)d_in[13];
    const float* W_hh = (const float*)d_in[14];
    const float* b_ih = (const float*)d_in[15];
    const float* b_hh = (const float*)d_in[16];
    const float* W_o1 = (const float*)d_in[17];
    const float* b_o1 = (const float*)d_in[18];
    const float* W_o2 = (const float*)d_in[19];
    const float* b_o2 = (const float*)d_in[20];
    float* out = (float*)d_out;

    char* ws = (char*)d_ws;
    size_t off = 0;
    auto alloc = [&](size_t bytes) -> void* {
        void* p = ws + off;
        off = (off + bytes + 255) & ~(size_t)255;
        return p;
    };
    int* segcnt    = (int*)alloc((size_t)T * N * SEG * 4);
    int* counts    = (int*)alloc(2048 * 4);
    int* sv        = (int*)alloc((size_t)T * N * CAP * 4);
    float* inorm   = (float*)alloc((size_t)NDIM * 4);
    float* partA   = (float*)alloc((size_t)8 * H1 * B * 4);
    float* AbT     = (float*)alloc((size_t)H1 * B * 4);
    float* W1T     = (float*)alloc((size_t)WVD * H1 * 4);
    float* Wp      = (float*)alloc((size_t)2 * N * H1 * 4);
    float* embs    = (float*)alloc((size_t)N * EMB * 4);
    float* embsT   = (float*)alloc((size_t)EMB * N * 4);
    float* Ahat    = (float*)alloc((size_t)T * N * RC * 4);
    float* wbuf    = (float*)alloc((size_t)T * N * CAP * 64 * 4);
    float* sT      = (float*)alloc((size_t)(STEPS + 1) * NDIM * B * 4);

    k_f1<<<F1_TOT, 256, 0, stream>>>(edge_u, segcnt, inputs, W_in1, partA, W1T,
                                     wordvecs, W_emb, b_emb, embs, embsT);
    k_f2<<<F2_TOT, 256, 0, stream>>>(partA, AbT, wordvecs, W1T, Wp,
                                     embsT, rel_mats, Ahat);
    k_f3<<<F3_TOT, 256, 0, stream>>>(edge_u, edge_v, segcnt,
                                     embs, Ahat, wbuf, inorm, counts, sv,
                                     AbT, Wp, b_in1, W_in2, b_in2, sT);

    for (int s = 0; s < STEPS; s++) {
        int last = (s == STEPS - 1) ? 1 : 0;
        k_step<<<N, 256, 0, stream>>>(counts, sv, wbuf, inorm, sT, s,
                                      W_ih, W_hh, b_ih, b_hh,
                                      W_o1, b_o1, W_o2, b_o2,
                                      sT + (size_t)(s + 1) * NDIM * B, out, last);
    }
}